// Round 1
// baseline (3758.713 us; speedup 1.0000x reference)
//
#include <hip/hip_runtime.h>
#include <math.h>

#define RR   32
#define RB   4
#define CIN  32
#define CO   64
#define NP   32768
#define SD   256
#define NVOX (RR*RR*RR)       // 32768
#define GRP  8
#define CPG  8                // channels per group
#define GN_CNT 262144.0f      // 8 channels * 32768 elements, same for every GN here

__device__ inline float silu_f(float x){ return x / (1.f + __expf(-x)); }

// ---------------- repack conv3d weights (O,I,3,3,3) -> [tap][ci][oc] ----------------
__global__ void k_repack(const float* __restrict__ w, float* __restrict__ wt){
    int i = blockIdx.x*blockDim.x + threadIdx.x;       // i = (oc*64+ci)*27+tap
    if (i >= CO*CO*27) return;
    int tap = i % 27;
    int ci  = (i/27) % CO;
    int oc  = i/(27*CO);
    wt[(tap*CO + ci)*CO + oc] = w[i];
}

// ---------------- AdaIN params: s,b = style @ W^T + bias ----------------
__global__ void k_adain(const float* __restrict__ style, const float* __restrict__ w_as,
                        const float* __restrict__ b_as, const float* __restrict__ w_ab,
                        const float* __restrict__ b_ab, float* __restrict__ sout,
                        float* __restrict__ bout){
    int t = threadIdx.x;            // 256 = B*CO
    int b = t >> 6, o = t & 63;
    const float* st = style + b*SD;
    float accs = b_as[o], accb = b_ab[o];
    for (int k=0;k<SD;k++){ float sv = st[k]; accs += sv*w_as[o*SD+k]; accb += sv*w_ab[o*SD+k]; }
    sout[t]=accs; bout[t]=accb;
}

// ---------------- per-batch coord min/max ----------------
__global__ void k_minmax(const float* __restrict__ coords, float* __restrict__ vmm){
    int b = blockIdx.x; int t = threadIdx.x;
    float mn[3]={1e30f,1e30f,1e30f}, mx[3]={-1e30f,-1e30f,-1e30f};
    const float* cp = coords + (size_t)b*NP*3;
    for (int n=t;n<NP;n+=256){
        #pragma unroll
        for(int d=0;d<3;d++){ float v = cp[n*3+d]; mn[d]=fminf(mn[d],v); mx[d]=fmaxf(mx[d],v);}
    }
    __shared__ float smn[256][3], smx[256][3];
    #pragma unroll
    for(int d=0;d<3;d++){ smn[t][d]=mn[d]; smx[t][d]=mx[d]; }
    __syncthreads();
    for(int s=128;s>0;s>>=1){
        if(t<s){
            #pragma unroll
            for(int d=0;d<3;d++){
                smn[t][d]=fminf(smn[t][d],smn[t+s][d]);
                smx[t][d]=fmaxf(smx[t][d],smx[t+s][d]);
            }
        }
        __syncthreads();
    }
    if(t<3){ vmm[b*6+t]=smn[0][t]; vmm[b*6+3+t]=smx[0][t]; }
}

// ---------------- point_in conv1x1 (pre-GN) + GN stats ----------------
__global__ __launch_bounds__(256) void k_pin(const float* __restrict__ feats, const float* __restrict__ w_pin,
                      float* __restrict__ ybuf, float* __restrict__ stats){
    __shared__ float wl[CO*CIN];   // 8 KB
    __shared__ float sred[GRP*2];
    int t = threadIdx.x;
    for (int i=t;i<CO*CIN;i+=256) wl[i]=w_pin[i];
    if (t<GRP*2) sred[t]=0.f;
    __syncthreads();
    int p = blockIdx.x*256 + t;
    int b = p >> 15;               // NP = 2^15
    int n = p & (NP-1);
    const float* fp = feats + (size_t)b*CIN*NP + n;
    float f[CIN];
    #pragma unroll
    for(int c=0;c<CIN;c++) f[c]=fp[(size_t)c*NP];
    float* yo = ybuf + (size_t)p*CO;
    for (int og=0;og<GRP;og++){
        float gs=0.f, gq=0.f;
        float vals[CPG];
        #pragma unroll
        for (int j=0;j<CPG;j++){
            int o = og*CPG + j;
            float acc=0.f;
            #pragma unroll
            for(int c=0;c<CIN;c++) acc += wl[o*CIN+c]*f[c];
            vals[j]=acc; gs+=acc; gq+=acc*acc;
        }
        float4* d = (float4*)(yo + og*CPG);
        d[0] = make_float4(vals[0],vals[1],vals[2],vals[3]);
        d[1] = make_float4(vals[4],vals[5],vals[6],vals[7]);
        #pragma unroll
        for (int off=32; off>=1; off>>=1){ gs += __shfl_down(gs, off); gq += __shfl_down(gq, off); }
        if ((t&63)==0){ atomicAdd(&sred[og*2], gs); atomicAdd(&sred[og*2+1], gq); }
    }
    __syncthreads();
    if (t<GRP){ atomicAdd(&stats[(b*GRP+t)*2], sred[t*2]); atomicAdd(&stats[(b*GRP+t)*2+1], sred[t*2+1]); }
}

// ---------------- GN+SiLU on points, then scatter into voxels ----------------
__global__ __launch_bounds__(256) void k_scatter(const float* __restrict__ ybuf, const float* __restrict__ stats,
                          const float* __restrict__ gamma, const float* __restrict__ beta,
                          const float* __restrict__ coords, const float* __restrict__ vmm,
                          float* __restrict__ vox, float* __restrict__ cnt){
    int t = threadIdx.x;
    int p = blockIdx.x*256+t;
    int b = p >> 15, n = p & (NP-1);
    float mean[GRP], inv[GRP];
    #pragma unroll
    for (int g=0; g<GRP; g++){
        float s = stats[(b*GRP+g)*2], q = stats[(b*GRP+g)*2+1];
        float m = s / GN_CNT;
        float v = q / GN_CNT - m*m;
        mean[g]=m; inv[g]=rsqrtf(v + 1e-5f);
    }
    const float* cp = coords + (size_t)(b*NP + n)*3;
    int id[3];
    #pragma unroll
    for(int d=0;d<3;d++){
        float vmin = vmm[b*6+d], vmax = vmm[b*6+3+d];
        float nr = (cp[d]-vmin)/fmaxf(vmax-vmin,1e-8f)*(RR-1);
        int ii = (int)rintf(nr);
        id[d] = min(max(ii,0),RR-1);
    }
    int flat = (id[0]*RR + id[1])*RR + id[2];
    float* vp = vox + ((size_t)(b*NVOX + flat))*CO;
    const float* yp = ybuf + (size_t)p*CO;
    #pragma unroll
    for (int o=0;o<CO;o++){
        int g = o>>3;
        float v = (yp[o]-mean[g])*inv[g]*gamma[o] + beta[o];
        v = silu_f(v);
        atomicAdd(&vp[o], v);
    }
    atomicAdd(&cnt[b*NVOX+flat], 1.f);
}

// ---------------- vox /= max(cnt,1) ----------------
__global__ void k_divide(float* __restrict__ vox, const float* __restrict__ cnt){
    size_t i = (size_t)blockIdx.x*256 + threadIdx.x;     // float4 index
    size_t tot = (size_t)RB*NVOX*CO/4;
    if (i>=tot) return;
    size_t e = i*4;
    size_t bv = e >> 6;                                   // /CO
    float rc = 1.f/fmaxf(cnt[bv], 1.f);
    float4* vp = (float4*)vox;
    float4 v = vp[i];
    v.x*=rc; v.y*=rc; v.z*=rc; v.w*=rc;
    vp[i]=v;
}

// ---------------- conv3d 3x3x3 (pre-GN) + GN stats ----------------
__global__ __launch_bounds__(256) void k_conv3d(const float* __restrict__ vin, const float* __restrict__ wt,
                        float* __restrict__ vout, float* __restrict__ stats){
    __shared__ float inl[3][RR*65];       // ~25 KB, stride 65 to avoid bank conflicts
    __shared__ float sred[GRP*2];
    int t = threadIdx.x;
    int blk = blockIdx.x;                 // (b*32+z)*32+y
    int b = blk >> 10;
    int z = (blk >> 5) & 31;
    int y = blk & 31;
    int x   = t >> 3;
    int ocg = t & 7;
    if (t < GRP*2) sred[t] = 0.f;
    float acc[8];
    #pragma unroll
    for (int j=0;j<8;j++) acc[j]=0.f;
    for (int dz=0; dz<3; dz++){
        int zp = z + dz - 1;
        __syncthreads();
        for (int r=0;r<3;r++){
            int yp = y + r - 1;
            bool ok = (zp>=0 && zp<RR && yp>=0 && yp<RR);
            int e0 = t*8;
            int xx = e0 >> 6;
            int c0 = e0 & 63;
            float tmp[8];
            if (ok){
                const float4* s4 = (const float4*)(vin + (((size_t)((b*RR+zp)*RR+yp))*RR)*CO + e0);
                float4 a = s4[0], b4 = s4[1];
                tmp[0]=a.x; tmp[1]=a.y; tmp[2]=a.z; tmp[3]=a.w;
                tmp[4]=b4.x;tmp[5]=b4.y;tmp[6]=b4.z;tmp[7]=b4.w;
            } else {
                #pragma unroll
                for(int k=0;k<8;k++) tmp[k]=0.f;
            }
            float* dst = &inl[r][xx*65 + c0];
            #pragma unroll
            for(int k=0;k<8;k++) dst[k]=tmp[k];
        }
        __syncthreads();
        for (int dy=0; dy<3; dy++){
            for (int dx=0; dx<3; dx++){
                int xx = x + dx - 1;
                if (xx < 0 || xx >= RR) continue;
                const float* ip = &inl[dy][xx*65];
                const float* wp = wt + ((size_t)((dz*9+dy*3+dx)*CO))*CO + ocg*8;
                #pragma unroll 8
                for (int ci=0; ci<CO; ci++){
                    float iv = ip[ci];
                    const float4* w4 = (const float4*)(wp + ci*CO);
                    float4 wa = w4[0], wb = w4[1];
                    acc[0] += iv*wa.x; acc[1]+=iv*wa.y; acc[2]+=iv*wa.z; acc[3]+=iv*wa.w;
                    acc[4] += iv*wb.x; acc[5]+=iv*wb.y; acc[6]+=iv*wb.z; acc[7]+=iv*wb.w;
                }
            }
        }
    }
    float* op = vout + (((size_t)blk)*RR + x)*CO + ocg*8;
    ((float4*)op)[0] = make_float4(acc[0],acc[1],acc[2],acc[3]);
    ((float4*)op)[1] = make_float4(acc[4],acc[5],acc[6],acc[7]);
    float gs=0.f,gq=0.f;
    #pragma unroll
    for(int j=0;j<8;j++){ gs+=acc[j]; gq+=acc[j]*acc[j]; }
    #pragma unroll
    for (int off=8; off<64; off<<=1){ gs += __shfl_xor(gs, off); gq += __shfl_xor(gq, off); }
    if ((t&63)<8){ atomicAdd(&sred[ocg*2],gs); atomicAdd(&sred[ocg*2+1],gq); }
    __syncthreads();
    if (t<8){ atomicAdd(&stats[(b*GRP+t)*2], sred[t*2]); atomicAdd(&stats[(b*GRP+t)*2+1], sred[t*2+1]); }
}

// ---------------- elementwise GN finalize + SiLU (in place) ----------------
__global__ void k_gnfin(float* __restrict__ buf, const float* __restrict__ stats,
                        const float* __restrict__ gamma, const float* __restrict__ beta){
    size_t i = (size_t)blockIdx.x*256+threadIdx.x;     // float4 index
    size_t tot = (size_t)RB*NVOX*CO/4;
    if (i>=tot) return;
    size_t e = i*4;
    int c = (int)(e & 63);
    int b = (int)(e >> 21);                             // NVOX*CO = 2^21
    int g = c >> 3;
    float s = stats[(b*GRP+g)*2], q = stats[(b*GRP+g)*2+1];
    float m = s/GN_CNT;
    float v = q/GN_CNT - m*m;
    float inv = rsqrtf(v+1e-5f);
    float4* p = (float4*)buf;
    float4 val = p[i];
    float* vv = (float*)&val;
    #pragma unroll
    for(int k=0;k<4;k++){
        int cc = c+k;
        float u = (vv[k]-m)*inv*gamma[cc] + beta[cc];
        vv[k] = silu_f(u);
    }
    p[i]=val;
}

// ---------------- devoxelize (trilinear) + fuse conv1x1 (pre-GN) + stats ----------------
__global__ __launch_bounds__(256) void k_devox_fuse(const float* __restrict__ vox, const float* __restrict__ coords,
                             const float* __restrict__ vmm, const float* __restrict__ wf,
                             float* __restrict__ obuf, float* __restrict__ stats){
    __shared__ float wl[CO*CO];    // 16 KB
    __shared__ float sred[GRP*2];
    int t = threadIdx.x;
    for (int i=t;i<CO*CO;i+=256) wl[i]=wf[i];
    if (t<GRP*2) sred[t]=0.f;
    __syncthreads();
    int p = blockIdx.x*256+t;
    int b = p>>15, n = p&(NP-1);
    const float* cp = coords + (size_t)(b*NP+n)*3;
    float fr[3]; int x0[3];
    #pragma unroll
    for(int d=0;d<3;d++){
        float vmin=vmm[b*6+d], vmax=vmm[b*6+3+d];
        float nr = (cp[d]-vmin)/fmaxf(vmax-vmin,1e-8f)*(RR-1);
        nr = fminf(fmaxf(nr,0.f),(float)(RR-1));
        float fl = floorf(nr);
        x0[d]=(int)fl; fr[d]=nr-fl;
    }
    float dev[CO];
    #pragma unroll
    for(int c=0;c<CO;c++) dev[c]=0.f;
    #pragma unroll
    for (int k=0;k<8;k++){
        int d0=(k>>2)&1, d1=(k>>1)&1, d2=k&1;
        int i0=min(x0[0]+d0,RR-1), i1=min(x0[1]+d1,RR-1), i2=min(x0[2]+d2,RR-1);
        float w = (d0?fr[0]:1.f-fr[0])*(d1?fr[1]:1.f-fr[1])*(d2?fr[2]:1.f-fr[2]);
        const float4* vp = (const float4*)(vox + ((size_t)(b*NVOX) + (i0*RR+i1)*RR+i2)*CO);
        #pragma unroll
        for (int c4=0;c4<CO/4;c4++){
            float4 v=vp[c4];
            dev[c4*4+0]+=w*v.x; dev[c4*4+1]+=w*v.y; dev[c4*4+2]+=w*v.z; dev[c4*4+3]+=w*v.w;
        }
    }
    float* op = obuf + (size_t)p*CO;
    for (int og=0;og<GRP;og++){
        float gs=0.f,gq=0.f;
        float vals[CPG];
        #pragma unroll
        for(int j=0;j<CPG;j++){
            int o=og*CPG+j;
            float acc=0.f;
            #pragma unroll
            for(int c=0;c<CO;c++) acc+=wl[o*CO+c]*dev[c];
            vals[j]=acc; gs+=acc; gq+=acc*acc;
        }
        ((float4*)(op+og*CPG))[0]=make_float4(vals[0],vals[1],vals[2],vals[3]);
        ((float4*)(op+og*CPG))[1]=make_float4(vals[4],vals[5],vals[6],vals[7]);
        #pragma unroll
        for(int off=32;off>=1;off>>=1){ gs+=__shfl_down(gs,off); gq+=__shfl_down(gq,off); }
        if((t&63)==0){ atomicAdd(&sred[og*2],gs); atomicAdd(&sred[og*2+1],gq); }
    }
    __syncthreads();
    if(t<GRP){ atomicAdd(&stats[(b*GRP+t)*2], sred[t*2]); atomicAdd(&stats[(b*GRP+t)*2+1], sred[t*2+1]); }
}

// ---------------- final: GN+SiLU + skip conv + AdaIN, write (B,C,N) ----------------
__global__ __launch_bounds__(256) void k_final(const float* __restrict__ obuf, const float* __restrict__ stats,
                        const float* __restrict__ gamma, const float* __restrict__ beta,
                        const float* __restrict__ feats, const float* __restrict__ wskip,
                        const float* __restrict__ ada_s, const float* __restrict__ ada_b,
                        float* __restrict__ out){
    __shared__ float wl[CO*CIN];   // 8 KB
    int t=threadIdx.x;
    for(int i=t;i<CO*CIN;i+=256) wl[i]=wskip[i];
    __syncthreads();
    int p = blockIdx.x*256+t;
    int b=p>>15, n=p&(NP-1);
    float mean[GRP], inv[GRP];
    #pragma unroll
    for(int g=0;g<GRP;g++){
        float s=stats[(b*GRP+g)*2], q=stats[(b*GRP+g)*2+1];
        float m=s/GN_CNT;
        float v=q/GN_CNT-m*m;
        mean[g]=m; inv[g]=rsqrtf(v+1e-5f);
    }
    float f[CIN];
    const float* fp=feats + (size_t)b*CIN*NP + n;
    #pragma unroll
    for(int c=0;c<CIN;c++) f[c]=fp[(size_t)c*NP];
    const float* ip = obuf + (size_t)p*CO;
    float* op = out + (size_t)b*CO*NP + n;
    for(int o=0;o<CO;o++){
        int g=o>>3;
        float u=(ip[o]-mean[g])*inv[g]*gamma[o]+beta[o];
        u=silu_f(u);
        float sk=0.f;
        #pragma unroll
        for(int c=0;c<CIN;c++) sk+=wl[o*CIN+c]*f[c];
        float s=ada_s[b*CO+o], bb=ada_b[b*CO+o];
        op[(size_t)o*NP] = (u+sk)*(1.f+s)+bb;
    }
}

extern "C" void kernel_launch(void* const* d_in, const int* in_sizes, int n_in,
                              void* d_out, int out_size, void* d_ws, size_t ws_size,
                              hipStream_t stream){
    const float* feats =(const float*)d_in[0];
    const float* coords=(const float*)d_in[1];
    const float* style =(const float*)d_in[2];
    const float* w_pin =(const float*)d_in[3];
    const float* g_pin =(const float*)d_in[4];
    const float* b_pin =(const float*)d_in[5];
    const float* w_v1  =(const float*)d_in[6];
    const float* g_v1  =(const float*)d_in[7];
    const float* b_v1  =(const float*)d_in[8];
    const float* w_v2  =(const float*)d_in[9];
    const float* g_v2  =(const float*)d_in[10];
    const float* b_v2  =(const float*)d_in[11];
    const float* w_fuse=(const float*)d_in[12];
    const float* g_f   =(const float*)d_in[13];
    const float* b_f   =(const float*)d_in[14];
    const float* w_skip=(const float*)d_in[15];
    const float* w_as  =(const float*)d_in[16];
    const float* b_as  =(const float*)d_in[17];
    const float* w_ab  =(const float*)d_in[18];
    const float* b_ab  =(const float*)d_in[19];
    float* out=(float*)d_out;
    float* ws =(float*)d_ws;

    const size_t BIG = (size_t)RB*NVOX*CO;       // 8388608 floats
    float* bufA  = ws;
    float* bufB  = ws + BIG;
    float* cnt   = ws + 2*BIG;                   // RB*NVOX
    float* stats = cnt + (size_t)RB*NVOX;        // 4 sets * 64 floats
    float* vmm   = stats + 4*GRP*RB*2;           // 24
    float* ada_s = vmm + 24;                     // 256
    float* ada_b = ada_s + RB*CO;                // 256
    float* wT1   = ada_b + RB*CO;                // 110592
    float* wT2   = wT1 + (size_t)CO*CO*27;       // 110592

    hipMemsetAsync(bufA, 0, BIG*sizeof(float), stream);
    hipMemsetAsync(cnt, 0, ((size_t)RB*NVOX + 4*GRP*RB*2)*sizeof(float), stream);

    k_repack<<<(CO*CO*27+255)/256,256,0,stream>>>(w_v1, wT1);
    k_repack<<<(CO*CO*27+255)/256,256,0,stream>>>(w_v2, wT2);
    k_adain<<<1,256,0,stream>>>(style,w_as,b_as,w_ab,b_ab,ada_s,ada_b);
    k_minmax<<<RB,256,0,stream>>>(coords,vmm);

    float* st0=stats;
    float* st1=st0+RB*GRP*2;
    float* st2=st1+RB*GRP*2;
    float* st3=st2+RB*GRP*2;

    k_pin<<<RB*NP/256,256,0,stream>>>(feats,w_pin,bufB,st0);
    k_scatter<<<RB*NP/256,256,0,stream>>>(bufB,st0,g_pin,b_pin,coords,vmm,bufA,cnt);
    k_divide<<<(int)((BIG/4+255)/256),256,0,stream>>>(bufA,cnt);
    k_conv3d<<<RB*RR*RR,256,0,stream>>>(bufA,wT1,bufB,st1);
    k_gnfin<<<(int)((BIG/4+255)/256),256,0,stream>>>(bufB,st1,g_v1,b_v1);
    k_conv3d<<<RB*RR*RR,256,0,stream>>>(bufB,wT2,bufA,st2);
    k_gnfin<<<(int)((BIG/4+255)/256),256,0,stream>>>(bufA,st2,g_v2,b_v2);
    k_devox_fuse<<<RB*NP/256,256,0,stream>>>(bufA,coords,vmm,w_fuse,bufB,st3);
    k_final<<<RB*NP/256,256,0,stream>>>(bufB,st3,g_f,b_f,feats,w_skip,ada_s,ada_b,out);
}

// Round 2
// 1305.368 us; speedup vs baseline: 2.8794x; 2.8794x over previous
//
#include <hip/hip_runtime.h>
#include <hip/hip_bf16.h>
#include <math.h>

#define RR   32
#define RB   4
#define CIN  32
#define CO   64
#define NP   32768
#define SD   256
#define NVOX (RR*RR*RR)       // 32768
#define GRP  8
#define CPG  8
#define GN_CNT 262144.0f      // 8 ch * 32768 vox per group
#define PR   34               // padded resolution
#define PSLICE (PR*PR*CO)     // 73984   (U stride)
#define PROW   (PR*CO)        // 2176    (V stride)
#define PVOL   ((size_t)PR*PR*PR*CO)   // per-batch padded elems 2,515,456
#define BIGN   ((size_t)RB*NVOX*CO)    // 8,388,608

typedef __attribute__((ext_vector_type(8))) short short8;
typedef __attribute__((ext_vector_type(4))) float f32x4;

__device__ inline float silu_f(float x){ return x / (1.f + __expf(-x)); }
__device__ inline float bf2f(ushort u){ uint v = ((uint)u)<<16; return *(float*)&v; }
__device__ inline ushort f2bf(float x){ __hip_bfloat16 h = __float2bfloat16(x); return *(ushort*)&h; }

// ---------------- weight pack: (O,I,3,3,3) fp32 -> bf16 [t][kc][nt][lane][8] ----------------
__global__ void k_wpack(const float* __restrict__ w, short* __restrict__ wp){
    int i = blockIdx.x*256 + threadIdx.x;       // 27*2*4*64 = 13824
    if (i >= 27*2*4*64) return;
    int l  = i & 63;
    int nt = (i>>6) & 3;
    int kc = (i>>8) & 1;
    int t  = i>>9;
    int oc = nt*16 + (l&15);
    int cib = kc*32 + (l>>4)*8;
    ushort out[8];
    #pragma unroll
    for (int j=0;j<8;j++) out[j] = f2bf(w[((oc*CO + cib + j))*27 + t]);
    *(uint4*)(wp + (size_t)i*8) = *(uint4*)out;
}

// ---------------- AdaIN params ----------------
__global__ void k_adain(const float* __restrict__ style, const float* __restrict__ w_as,
                        const float* __restrict__ b_as, const float* __restrict__ w_ab,
                        const float* __restrict__ b_ab, float* __restrict__ sout,
                        float* __restrict__ bout){
    int t = threadIdx.x;            // 256 = B*CO
    int b = t >> 6, o = t & 63;
    const float* st = style + b*SD;
    float accs = b_as[o], accb = b_ab[o];
    for (int k=0;k<SD;k++){ float sv = st[k]; accs += sv*w_as[o*SD+k]; accb += sv*w_ab[o*SD+k]; }
    sout[t]=accs; bout[t]=accb;
}

// ---------------- per-batch coord min/max ----------------
__global__ void k_minmax(const float* __restrict__ coords, float* __restrict__ vmm){
    int b = blockIdx.x; int t = threadIdx.x;
    float mn[3]={1e30f,1e30f,1e30f}, mx[3]={-1e30f,-1e30f,-1e30f};
    const float* cp = coords + (size_t)b*NP*3;
    for (int n=t;n<NP;n+=256){
        #pragma unroll
        for(int d=0;d<3;d++){ float v = cp[n*3+d]; mn[d]=fminf(mn[d],v); mx[d]=fmaxf(mx[d],v);}
    }
    __shared__ float smn[256][3], smx[256][3];
    #pragma unroll
    for(int d=0;d<3;d++){ smn[t][d]=mn[d]; smx[t][d]=mx[d]; }
    __syncthreads();
    for(int s=128;s>0;s>>=1){
        if(t<s){
            #pragma unroll
            for(int d=0;d<3;d++){
                smn[t][d]=fminf(smn[t][d],smn[t+s][d]);
                smx[t][d]=fmaxf(smx[t][d],smx[t+s][d]);
            }
        }
        __syncthreads();
    }
    if(t<3){ vmm[b*6+t]=smn[0][t]; vmm[b*6+3+t]=smx[0][t]; }
}

// ---------------- point_in conv1x1 (pre-GN) + GN stats ----------------
__global__ __launch_bounds__(256) void k_pin(const float* __restrict__ feats, const float* __restrict__ w_pin,
                      float* __restrict__ ybuf, float* __restrict__ stats){
    __shared__ float wl[CO*CIN];
    __shared__ float sred[GRP*2];
    int t = threadIdx.x;
    for (int i=t;i<CO*CIN;i+=256) wl[i]=w_pin[i];
    if (t<GRP*2) sred[t]=0.f;
    __syncthreads();
    int p = blockIdx.x*256 + t;
    int b = p >> 15;
    int n = p & (NP-1);
    const float* fp = feats + (size_t)b*CIN*NP + n;
    float f[CIN];
    #pragma unroll
    for(int c=0;c<CIN;c++) f[c]=fp[(size_t)c*NP];
    float* yo = ybuf + (size_t)p*CO;
    for (int og=0;og<GRP;og++){
        float gs=0.f, gq=0.f;
        float vals[CPG];
        #pragma unroll
        for (int j=0;j<CPG;j++){
            int o = og*CPG + j;
            float acc=0.f;
            #pragma unroll
            for(int c=0;c<CIN;c++) acc += wl[o*CIN+c]*f[c];
            vals[j]=acc; gs+=acc; gq+=acc*acc;
        }
        float4* d = (float4*)(yo + og*CPG);
        d[0] = make_float4(vals[0],vals[1],vals[2],vals[3]);
        d[1] = make_float4(vals[4],vals[5],vals[6],vals[7]);
        #pragma unroll
        for (int off=32; off>=1; off>>=1){ gs += __shfl_down(gs, off); gq += __shfl_down(gq, off); }
        if ((t&63)==0){ atomicAdd(&sred[og*2], gs); atomicAdd(&sred[og*2+1], gq); }
    }
    __syncthreads();
    if (t<GRP){ atomicAdd(&stats[(b*GRP+t)*2], sred[t*2]); atomicAdd(&stats[(b*GRP+t)*2+1], sred[t*2+1]); }
}

// ---------------- GN+SiLU on points, scatter into fp32 voxel accumulator ----------------
__global__ __launch_bounds__(256) void k_scatter(const float* __restrict__ ybuf, const float* __restrict__ stats,
                          const float* __restrict__ gamma, const float* __restrict__ beta,
                          const float* __restrict__ coords, const float* __restrict__ vmm,
                          float* __restrict__ vox, float* __restrict__ cnt){
    int t = threadIdx.x;
    int p = blockIdx.x*256+t;
    int b = p >> 15, n = p & (NP-1);
    float mean[GRP], inv[GRP];
    #pragma unroll
    for (int g=0; g<GRP; g++){
        float s = stats[(b*GRP+g)*2], q = stats[(b*GRP+g)*2+1];
        float m = s / GN_CNT;
        float v = q / GN_CNT - m*m;
        mean[g]=m; inv[g]=rsqrtf(v + 1e-5f);
    }
    const float* cp = coords + (size_t)(b*NP + n)*3;
    int id[3];
    #pragma unroll
    for(int d=0;d<3;d++){
        float vmin = vmm[b*6+d], vmax = vmm[b*6+3+d];
        float nr = (cp[d]-vmin)/fmaxf(vmax-vmin,1e-8f)*(RR-1);
        int ii = (int)rintf(nr);
        id[d] = min(max(ii,0),RR-1);
    }
    int flat = (id[0]*RR + id[1])*RR + id[2];
    float* vp = vox + ((size_t)(b*NVOX + flat))*CO;
    const float* yp = ybuf + (size_t)p*CO;
    #pragma unroll
    for (int o=0;o<CO;o++){
        int g = o>>3;
        float v = (yp[o]-mean[g])*inv[g]*gamma[o] + beta[o];
        v = silu_f(v);
        atomicAdd(&vp[o], v);
    }
    atomicAdd(&cnt[b*NVOX+flat], 1.f);
}

// ---------------- divide by count + cast bf16 + write into zero-padded volume ----------------
__global__ __launch_bounds__(256) void k_pad(const float* __restrict__ acc, const float* __restrict__ cnt,
                      __hip_bfloat16* __restrict__ P){
    int i = blockIdx.x*256 + threadIdx.x;    // one per 8 channels: 4*32768*8
    int c8 = i & 7;
    int vox = (i>>3) & (NVOX-1);
    int b = i >> 18;
    float rc = 1.f/fmaxf(cnt[(b<<15)+vox], 1.f);
    const float4* s4 = (const float4*)(acc + ((size_t)i)*8);
    float4 a0 = s4[0], a1 = s4[1];
    ushort out[8];
    out[0]=f2bf(a0.x*rc); out[1]=f2bf(a0.y*rc); out[2]=f2bf(a0.z*rc); out[3]=f2bf(a0.w*rc);
    out[4]=f2bf(a1.x*rc); out[5]=f2bf(a1.y*rc); out[6]=f2bf(a1.z*rc); out[7]=f2bf(a1.w*rc);
    int u = vox>>10, v = (vox>>5)&31, w = vox&31;
    size_t pd = ((size_t)b*PVOL) + (size_t)(u+1)*PSLICE + (v+1)*PROW + (w+1)*CO + c8*8;
    *(uint4*)((ushort*)P + pd) = *(uint4*)out;
}

// ---------------- MFMA conv3d: padded bf16 volume -> raw bf16 (unpadded) + GN stats ----------------
__global__ __launch_bounds__(256) void k_conv_mfma(const __hip_bfloat16* __restrict__ P,
                        const short* __restrict__ wpack,
                        __hip_bfloat16* __restrict__ outv, float* __restrict__ stats){
    __shared__ __align__(16) char lds[9*PR*CO*2];   // 9 rows * 34 vox * 64ch bf16 = 39168 B
    int t = threadIdx.x;
    int blk = blockIdx.x;                 // (b*32+u)*32+v
    int b = blk >> 10;
    int u = (blk >> 5) & 31;
    int v = blk & 31;

    // ---- stage 9 padded rows into LDS with XOR swizzle (T2) ----
    const ushort* Pp = (const ushort*)P;
    for (int i = t; i < 9*272; i += 256){           // 272 chunks of 16B per row
        int r = i / 272;
        int chunk = i - r*272;
        size_t src = (size_t)b*PVOL + (size_t)(u + r/3)*PSLICE + (size_t)(v + r%3)*PROW + (size_t)chunk*8;
        uint4 val = *(const uint4*)(Pp + src);
        int vx = chunk >> 3;
        int colb = (chunk & 7) << 4;
        int dst = r*4352 + vx*128 + (colb ^ ((vx&7)<<4));
        *(uint4*)(lds + dst) = val;
    }
    __syncthreads();

    int l  = t & 63;
    int nt = t >> 6;                      // wave id = N-tile (16 oc)
    int lm = l & 15;
    int lk = l >> 4;
    int colb_base = lk*16;                // byte offset of this lane's 8-ci chunk (within 64-ci row)

    f32x4 acc0 = {0.f,0.f,0.f,0.f};
    f32x4 acc1 = {0.f,0.f,0.f,0.f};

    const short* wp = wpack + ((size_t)nt*64 + l)*8;   // [t][kc][nt][lane][8]
    for (int tap = 0; tap < 27; tap++){
        int r  = tap/3;
        int dx = tap - r*3;
        #pragma unroll
        for (int kc = 0; kc < 2; kc++){
            short8 bw = *(const short8*)(wp + ((size_t)(tap*2 + kc))*2048);
            int colb = colb_base + kc*64;
            int vx0 = lm + dx;
            int a0 = r*4352 + vx0*128 + (colb ^ ((vx0&7)<<4));
            int vx1 = vx0 + 16;
            int a1 = r*4352 + vx1*128 + (colb ^ ((vx1&7)<<4));
            short8 av0 = *(const short8*)(lds + a0);
            short8 av1 = *(const short8*)(lds + a1);
            acc0 = __builtin_amdgcn_mfma_f32_16x16x32_bf16(av0, bw, acc0, 0, 0, 0);
            acc1 = __builtin_amdgcn_mfma_f32_16x16x32_bf16(av1, bw, acc1, 0, 0, 0);
        }
    }

    // ---- store raw bf16 + GN stats ----
    int oc = nt*16 + lm;
    ushort* ob = (ushort*)outv;
    float s = 0.f, q = 0.f;
    #pragma unroll
    for (int j=0;j<4;j++){
        float v0 = acc0[j], v1 = acc1[j];
        s += v0 + v1; q += v0*v0 + v1*v1;
        int m = lk*4 + j;
        ob[((size_t)(blk*32 + m))*CO + oc]      = f2bf(v0);
        ob[((size_t)(blk*32 + 16 + m))*CO + oc] = f2bf(v1);
    }
    #pragma unroll
    for (int off : {1,2,4,16,32}){ s += __shfl_xor(s, off); q += __shfl_xor(q, off); }
    if (lk==0 && (lm&7)==0){
        int g = 2*nt + (lm>>3);
        atomicAdd(&stats[(b*GRP+g)*2],   s);
        atomicAdd(&stats[(b*GRP+g)*2+1], q);
    }
}

// ---------------- GN finalize + SiLU + cast into padded bf16 volume ----------------
__global__ __launch_bounds__(256) void k_gnfin_cast(const __hip_bfloat16* __restrict__ raw, const float* __restrict__ stats,
                        const float* __restrict__ gamma, const float* __restrict__ beta,
                        __hip_bfloat16* __restrict__ P){
    int i = blockIdx.x*256 + threadIdx.x;    // one per 8 channels
    int c8 = i & 7;
    int vox = (i>>3) & (NVOX-1);
    int b = i >> 18;
    float s = stats[(b*GRP+c8)*2], qq = stats[(b*GRP+c8)*2+1];
    float m = s/GN_CNT;
    float inv = rsqrtf(qq/GN_CNT - m*m + 1e-5f);
    uint4 rv = *(const uint4*)((const ushort*)raw + ((size_t)i)*8);
    ushort* us = (ushort*)&rv;
    ushort out[8];
    #pragma unroll
    for (int j=0;j<8;j++){
        int c = c8*8+j;
        float x = (bf2f(us[j]) - m)*inv*gamma[c] + beta[c];
        out[j] = f2bf(silu_f(x));
    }
    int u = vox>>10, v = (vox>>5)&31, w = vox&31;
    size_t pd = ((size_t)b*PVOL) + (size_t)(u+1)*PSLICE + (v+1)*PROW + (w+1)*CO + c8*8;
    *(uint4*)((ushort*)P + pd) = *(uint4*)out;
}

// ---------------- GN finalize + SiLU, bf16 in place ----------------
__global__ __launch_bounds__(256) void k_gnfin_b16(__hip_bfloat16* __restrict__ raw, const float* __restrict__ stats,
                        const float* __restrict__ gamma, const float* __restrict__ beta){
    int i = blockIdx.x*256 + threadIdx.x;
    int c8 = i & 7;
    int b = i >> 18;
    float s = stats[(b*GRP+c8)*2], qq = stats[(b*GRP+c8)*2+1];
    float m = s/GN_CNT;
    float inv = rsqrtf(qq/GN_CNT - m*m + 1e-5f);
    uint4 rv = *(const uint4*)((const ushort*)raw + ((size_t)i)*8);
    ushort* us = (ushort*)&rv;
    ushort out[8];
    #pragma unroll
    for (int j=0;j<8;j++){
        int c = c8*8+j;
        float x = (bf2f(us[j]) - m)*inv*gamma[c] + beta[c];
        out[j] = f2bf(silu_f(x));
    }
    *(uint4*)((ushort*)raw + ((size_t)i)*8) = *(uint4*)out;
}

// ---------------- devoxelize (bf16 gather) + fuse conv1x1 (pre-GN) + stats ----------------
__global__ __launch_bounds__(256) void k_devox_fuse(const __hip_bfloat16* __restrict__ vox, const float* __restrict__ coords,
                             const float* __restrict__ vmm, const float* __restrict__ wf,
                             float* __restrict__ obuf, float* __restrict__ stats){
    __shared__ float wl[CO*CO];
    __shared__ float sred[GRP*2];
    int t = threadIdx.x;
    for (int i=t;i<CO*CO;i+=256) wl[i]=wf[i];
    if (t<GRP*2) sred[t]=0.f;
    __syncthreads();
    int p = blockIdx.x*256+t;
    int b = p>>15, n = p&(NP-1);
    const float* cp = coords + (size_t)(b*NP+n)*3;
    float fr[3]; int x0[3];
    #pragma unroll
    for(int d=0;d<3;d++){
        float vmin=vmm[b*6+d], vmax=vmm[b*6+3+d];
        float nr = (cp[d]-vmin)/fmaxf(vmax-vmin,1e-8f)*(RR-1);
        nr = fminf(fmaxf(nr,0.f),(float)(RR-1));
        float fl = floorf(nr);
        x0[d]=(int)fl; fr[d]=nr-fl;
    }
    float dev[CO];
    #pragma unroll
    for(int c=0;c<CO;c++) dev[c]=0.f;
    #pragma unroll
    for (int k=0;k<8;k++){
        int d0=(k>>2)&1, d1=(k>>1)&1, d2=k&1;
        int i0=min(x0[0]+d0,RR-1), i1=min(x0[1]+d1,RR-1), i2=min(x0[2]+d2,RR-1);
        float w = (d0?fr[0]:1.f-fr[0])*(d1?fr[1]:1.f-fr[1])*(d2?fr[2]:1.f-fr[2]);
        const ushort* vp = (const ushort*)vox + ((size_t)(b*NVOX) + (i0*RR+i1)*RR+i2)*CO;
        #pragma unroll
        for (int cc=0; cc<8; cc++){
            uint4 raw = *(const uint4*)(vp + cc*8);
            ushort* us = (ushort*)&raw;
            #pragma unroll
            for (int j=0;j<8;j++) dev[cc*8+j] += w * bf2f(us[j]);
        }
    }
    float* op = obuf + (size_t)p*CO;
    for (int og=0;og<GRP;og++){
        float gs=0.f,gq=0.f;
        float vals[CPG];
        #pragma unroll
        for(int j=0;j<CPG;j++){
            int o=og*CPG+j;
            float acc=0.f;
            #pragma unroll
            for(int c=0;c<CO;c++) acc+=wl[o*CO+c]*dev[c];
            vals[j]=acc; gs+=acc; gq+=acc*acc;
        }
        ((float4*)(op+og*CPG))[0]=make_float4(vals[0],vals[1],vals[2],vals[3]);
        ((float4*)(op+og*CPG))[1]=make_float4(vals[4],vals[5],vals[6],vals[7]);
        #pragma unroll
        for(int off=32;off>=1;off>>=1){ gs+=__shfl_down(gs,off); gq+=__shfl_down(gq,off); }
        if((t&63)==0){ atomicAdd(&sred[og*2],gs); atomicAdd(&sred[og*2+1],gq); }
    }
    __syncthreads();
    if(t<GRP){ atomicAdd(&stats[(b*GRP+t)*2], sred[t*2]); atomicAdd(&stats[(b*GRP+t)*2+1], sred[t*2+1]); }
}

// ---------------- final: GN+SiLU + skip conv + AdaIN, write (B,C,N) ----------------
__global__ __launch_bounds__(256) void k_final(const float* __restrict__ obuf, const float* __restrict__ stats,
                        const float* __restrict__ gamma, const float* __restrict__ beta,
                        const float* __restrict__ feats, const float* __restrict__ wskip,
                        const float* __restrict__ ada_s, const float* __restrict__ ada_b,
                        float* __restrict__ out){
    __shared__ float wl[CO*CIN];
    int t=threadIdx.x;
    for(int i=t;i<CO*CIN;i+=256) wl[i]=wskip[i];
    __syncthreads();
    int p = blockIdx.x*256+t;
    int b=p>>15, n=p&(NP-1);
    float mean[GRP], inv[GRP];
    #pragma unroll
    for(int g=0;g<GRP;g++){
        float s=stats[(b*GRP+g)*2], q=stats[(b*GRP+g)*2+1];
        float m=s/GN_CNT;
        float v=q/GN_CNT-m*m;
        mean[g]=m; inv[g]=rsqrtf(v+1e-5f);
    }
    float f[CIN];
    const float* fp=feats + (size_t)b*CIN*NP + n;
    #pragma unroll
    for(int c=0;c<CIN;c++) f[c]=fp[(size_t)c*NP];
    const float* ip = obuf + (size_t)p*CO;
    float* op = out + (size_t)b*CO*NP + n;
    for(int o=0;o<CO;o++){
        int g=o>>3;
        float u=(ip[o]-mean[g])*inv[g]*gamma[o]+beta[o];
        u=silu_f(u);
        float sk=0.f;
        #pragma unroll
        for(int c=0;c<CIN;c++) sk+=wl[o*CIN+c]*f[c];
        float s=ada_s[b*CO+o], bb=ada_b[b*CO+o];
        op[(size_t)o*NP] = (u+sk)*(1.f+s)+bb;
    }
}

extern "C" void kernel_launch(void* const* d_in, const int* in_sizes, int n_in,
                              void* d_out, int out_size, void* d_ws, size_t ws_size,
                              hipStream_t stream){
    const float* feats =(const float*)d_in[0];
    const float* coords=(const float*)d_in[1];
    const float* style =(const float*)d_in[2];
    const float* w_pin =(const float*)d_in[3];
    const float* g_pin =(const float*)d_in[4];
    const float* b_pin =(const float*)d_in[5];
    const float* w_v1  =(const float*)d_in[6];
    const float* g_v1  =(const float*)d_in[7];
    const float* b_v1  =(const float*)d_in[8];
    const float* w_v2  =(const float*)d_in[9];
    const float* g_v2  =(const float*)d_in[10];
    const float* b_v2  =(const float*)d_in[11];
    const float* w_fuse=(const float*)d_in[12];
    const float* g_f   =(const float*)d_in[13];
    const float* b_f   =(const float*)d_in[14];
    const float* w_skip=(const float*)d_in[15];
    const float* w_as  =(const float*)d_in[16];
    const float* b_as  =(const float*)d_in[17];
    const float* w_ab  =(const float*)d_in[18];
    const float* b_ab  =(const float*)d_in[19];
    float* out=(float*)d_out;
    float* ws =(float*)d_ws;

    // workspace layout (floats)
    float* R1    = ws;                              // 33.5 MB: ybuf / P1,P2(bf16) / obuf
    float* R2    = ws + BIGN;                       // 33.5 MB: vox accum / raw conv out (bf16)
    float* cnt   = ws + 2*BIGN;                     // 131072
    float* stats = cnt + (size_t)RB*NVOX;           // 256 (4 sets x 64)
    float* vmm   = stats + 256;                     // 24
    float* ada_s = vmm + 24;                        // 256
    float* ada_b = ada_s + RB*CO;                   // 256
    short* wp1   = (short*)(ada_b + RB*CO);         // 110592 shorts
    short* wp2   = wp1 + 27*2*4*64*8;               // 110592 shorts

    float* st0 = stats;
    float* st1 = stats + 64;
    float* st2 = stats + 128;
    float* st3 = stats + 192;

    __hip_bfloat16* Pvol = (__hip_bfloat16*)R1;     // padded volume (aliases R1)
    __hip_bfloat16* raw  = (__hip_bfloat16*)R2;     // raw conv outputs (aliases R2)

    // zero: accumulation buffer, counts+stats
    hipMemsetAsync(R2, 0, BIGN*sizeof(float), stream);
    hipMemsetAsync(cnt, 0, ((size_t)RB*NVOX + 256)*sizeof(float), stream);

    k_wpack<<<54,256,0,stream>>>(w_v1, wp1);
    k_wpack<<<54,256,0,stream>>>(w_v2, wp2);
    k_adain<<<1,256,0,stream>>>(style,w_as,b_as,w_ab,b_ab,ada_s,ada_b);
    k_minmax<<<RB,256,0,stream>>>(coords,vmm);

    k_pin<<<RB*NP/256,256,0,stream>>>(feats,w_pin,R1,st0);
    k_scatter<<<RB*NP/256,256,0,stream>>>(R1,st0,g_pin,b_pin,coords,vmm,R2,cnt);

    // zero the padded volume (borders) then fill interior
    hipMemsetAsync(R1, 0, (size_t)RB*PVOL*sizeof(__hip_bfloat16), stream);
    k_pad<<<RB*NVOX*8/256,256,0,stream>>>(R2,cnt,Pvol);

    k_conv_mfma<<<RB*RR*RR,256,0,stream>>>(Pvol, wp1, raw, st1);
    k_gnfin_cast<<<RB*NVOX*8/256,256,0,stream>>>(raw, st1, g_v1, b_v1, Pvol);   // borders stay zero
    k_conv_mfma<<<RB*RR*RR,256,0,stream>>>(Pvol, wp2, raw, st2);
    k_gnfin_b16<<<RB*NVOX*8/256,256,0,stream>>>(raw, st2, g_v2, b_v2);

    k_devox_fuse<<<RB*NP/256,256,0,stream>>>(raw, coords, vmm, w_fuse, R1, st3);
    k_final<<<RB*NP/256,256,0,stream>>>(R1, st3, g_f, b_f, feats, w_skip, ada_s, ada_b, out);
}

// Round 3
// 870.572 us; speedup vs baseline: 4.3175x; 1.4994x over previous
//
#include <hip/hip_runtime.h>
#include <hip/hip_bf16.h>
#include <math.h>

#define RR   32
#define RB   4
#define CIN  32
#define CO   64
#define NP   32768
#define SD   256
#define NVOX (RR*RR*RR)       // 32768
#define GRP  8
#define CPG  8
#define GN_CNT 262144.0f      // 8 ch * 32768 vox per group
#define PR   34               // padded resolution
#define PSLICE (PR*PR*CO)     // 73984   (U stride)
#define PROW   (PR*CO)        // 2176    (V stride)
#define PVOL   ((size_t)PR*PR*PR*CO)   // per-batch padded elems 2,515,456
#define BIGN   ((size_t)RB*NVOX*CO)    // 8,388,608

typedef __attribute__((ext_vector_type(8))) short short8;
typedef __attribute__((ext_vector_type(4))) float f32x4;

__device__ inline float silu_f(float x){ return x / (1.f + __expf(-x)); }
__device__ inline float bf2f(ushort u){ uint v = ((uint)u)<<16; return *(float*)&v; }
__device__ inline ushort f2bf(float x){ __hip_bfloat16 h = __float2bfloat16(x); return *(ushort*)&h; }

// ---------------- weight pack: (O,I,3,3,3) fp32 -> bf16 [t][kc][nt][lane][8] ----------------
__global__ void k_wpack(const float* __restrict__ w, short* __restrict__ wp){
    int i = blockIdx.x*256 + threadIdx.x;       // 27*2*4*64 = 13824
    if (i >= 27*2*4*64) return;
    int l  = i & 63;
    int nt = (i>>6) & 3;
    int kc = (i>>8) & 1;
    int t  = i>>9;
    int oc = nt*16 + (l&15);
    int cib = kc*32 + (l>>4)*8;
    ushort out[8];
    #pragma unroll
    for (int j=0;j<8;j++) out[j] = f2bf(w[((oc*CO + cib + j))*27 + t]);
    *(uint4*)(wp + (size_t)i*8) = *(uint4*)out;
}

// ---------------- AdaIN params ----------------
__global__ void k_adain(const float* __restrict__ style, const float* __restrict__ w_as,
                        const float* __restrict__ b_as, const float* __restrict__ w_ab,
                        const float* __restrict__ b_ab, float* __restrict__ sout,
                        float* __restrict__ bout){
    int t = threadIdx.x;            // 256 = B*CO
    int b = t >> 6, o = t & 63;
    const float* st = style + b*SD;
    float accs = b_as[o], accb = b_ab[o];
    for (int k=0;k<SD;k++){ float sv = st[k]; accs += sv*w_as[o*SD+k]; accb += sv*w_ab[o*SD+k]; }
    sout[t]=accs; bout[t]=accb;
}

// ---------------- per-batch coord min/max ----------------
__global__ void k_minmax(const float* __restrict__ coords, float* __restrict__ vmm){
    int b = blockIdx.x; int t = threadIdx.x;
    float mn[3]={1e30f,1e30f,1e30f}, mx[3]={-1e30f,-1e30f,-1e30f};
    const float* cp = coords + (size_t)b*NP*3;
    for (int n=t;n<NP;n+=256){
        #pragma unroll
        for(int d=0;d<3;d++){ float v = cp[n*3+d]; mn[d]=fminf(mn[d],v); mx[d]=fmaxf(mx[d],v);}
    }
    __shared__ float smn[256][3], smx[256][3];
    #pragma unroll
    for(int d=0;d<3;d++){ smn[t][d]=mn[d]; smx[t][d]=mx[d]; }
    __syncthreads();
    for(int s=128;s>0;s>>=1){
        if(t<s){
            #pragma unroll
            for(int d=0;d<3;d++){
                smn[t][d]=fminf(smn[t][d],smn[t+s][d]);
                smx[t][d]=fmaxf(smx[t][d],smx[t+s][d]);
            }
        }
        __syncthreads();
    }
    if(t<3){ vmm[b*6+t]=smn[0][t]; vmm[b*6+3+t]=smx[0][t]; }
}

// ---------------- point_in conv1x1 (pre-GN, bf16 out) + GN stats ----------------
__global__ __launch_bounds__(256) void k_pin(const float* __restrict__ feats, const float* __restrict__ w_pin,
                      ushort* __restrict__ ybuf, float* __restrict__ stats){
    __shared__ float wl[CO*CIN];
    __shared__ float sred[GRP*2];
    int t = threadIdx.x;
    for (int i=t;i<CO*CIN;i+=256) wl[i]=w_pin[i];
    if (t<GRP*2) sred[t]=0.f;
    __syncthreads();
    int p = blockIdx.x*256 + t;
    int b = p >> 15;
    int n = p & (NP-1);
    const float* fp = feats + (size_t)b*CIN*NP + n;
    float f[CIN];
    #pragma unroll
    for(int c=0;c<CIN;c++) f[c]=fp[(size_t)c*NP];
    ushort* yo = ybuf + (size_t)p*CO;
    for (int og=0;og<GRP;og++){
        float gs=0.f, gq=0.f;
        ushort vals[8];
        #pragma unroll
        for (int j=0;j<CPG;j++){
            int o = og*CPG + j;
            float acc=0.f;
            #pragma unroll
            for(int c=0;c<CIN;c++) acc += wl[o*CIN+c]*f[c];
            vals[j]=f2bf(acc); gs+=acc; gq+=acc*acc;
        }
        *(uint4*)(yo + og*CPG) = *(uint4*)vals;
        #pragma unroll
        for (int off=32; off>=1; off>>=1){ gs += __shfl_down(gs, off); gq += __shfl_down(gq, off); }
        if ((t&63)==0){ atomicAdd(&sred[og*2], gs); atomicAdd(&sred[og*2+1], gq); }
    }
    __syncthreads();
    if (t<GRP){ atomicAdd(&stats[(b*GRP+t)*2], sred[t*2]); atomicAdd(&stats[(b*GRP+t)*2+1], sred[t*2+1]); }
}

// ---------------- voxel id per point + per-voxel count ----------------
__global__ __launch_bounds__(256) void k_count(const float* __restrict__ coords, const float* __restrict__ vmm,
                        int* __restrict__ pid, int* __restrict__ cnt){
    int p = blockIdx.x*256 + threadIdx.x;
    int b = p >> 15, n = p & (NP-1);
    const float* cp = coords + (size_t)(b*NP + n)*3;
    int id[3];
    #pragma unroll
    for(int d=0;d<3;d++){
        float vmin = vmm[b*6+d], vmax = vmm[b*6+3+d];
        float nr = (cp[d]-vmin)/fmaxf(vmax-vmin,1e-8f)*(RR-1);
        int ii = (int)rintf(nr);
        id[d] = min(max(ii,0),RR-1);
    }
    int flat = (id[0]*RR + id[1])*RR + id[2];
    pid[p] = flat;
    atomicAdd(&cnt[(b<<15)+flat], 1);
}

// ---------------- per-batch exclusive scan of 32768 counts ----------------
__global__ __launch_bounds__(1024) void k_scan(const int* __restrict__ cnt, int* __restrict__ offs,
                        int* __restrict__ cursor){
    int b = blockIdx.x, t = threadIdx.x;
    const int* c = cnt + (b<<15);
    int base = t*32;
    int pref[32];
    int s = 0;
    #pragma unroll
    for (int k4=0;k4<8;k4++){
        int4 q = *(const int4*)(c + base + k4*4);
        pref[k4*4+0]=s; s+=q.x;
        pref[k4*4+1]=s; s+=q.y;
        pref[k4*4+2]=s; s+=q.z;
        pref[k4*4+3]=s; s+=q.w;
    }
    int lane = t & 63, w = t >> 6;
    int inc = s;
    #pragma unroll
    for (int off=1; off<64; off<<=1){ int u = __shfl_up(inc, off); if (lane>=off) inc += u; }
    __shared__ int wsum[16];
    if (lane==63) wsum[w]=inc;
    __syncthreads();
    int wexcl=0;
    for (int i=0;i<w;i++) wexcl += wsum[i];
    int texcl = wexcl + inc - s;
    int* o = offs + (b<<15) + base;
    int* cu = cursor + (b<<15) + base;
    #pragma unroll
    for (int k=0;k<32;k++){ int v = texcl + pref[k]; o[k]=v; cu[k]=v; }
}

// ---------------- place point indices into CSR order ----------------
__global__ __launch_bounds__(256) void k_fill(const int* __restrict__ pid, int* __restrict__ cursor,
                       int* __restrict__ order){
    int p = blockIdx.x*256 + threadIdx.x;
    int b = p >> 15, n = p & (NP-1);
    int v = pid[p];
    int slot = atomicAdd(&cursor[(b<<15)+v], 1);
    order[(b<<15)+slot] = n;
}

// ---------------- gather per voxel: GN+SiLU(y) average -> padded bf16 volume ----------------
__global__ __launch_bounds__(256) void k_gather_pad(const ushort* __restrict__ ybuf, const int* __restrict__ offs,
                             const int* __restrict__ order, const float* __restrict__ stats,
                             const float* __restrict__ gamma, const float* __restrict__ beta,
                             ushort* __restrict__ P){
    int i = blockIdx.x*256 + threadIdx.x;   // RB*NVOX*8
    int c8 = i & 7;
    int vox = (i>>3) & (NVOX-1);
    int b = i >> 18;
    float s = stats[(b*GRP+c8)*2], qq = stats[(b*GRP+c8)*2+1];
    float m = s/GN_CNT;
    float inv = rsqrtf(qq/GN_CNT - m*m + 1e-5f);
    float ga[8], be[8];
    #pragma unroll
    for (int k=0;k<8;k++){ ga[k]=gamma[c8*8+k]*inv; be[k]=beta[c8*8+k]-m*ga[k]; }
    int o0 = offs[(b<<15)+vox];
    int o1 = (vox==NVOX-1) ? NP : offs[(b<<15)+vox+1];
    float acc[8];
    #pragma unroll
    for (int k=0;k<8;k++) acc[k]=0.f;
    for (int j=o0; j<o1; j++){
        int n = order[(b<<15)+j];
        uint4 raw = *(const uint4*)(ybuf + ((size_t)((b<<15)+n))*CO + c8*8);
        ushort* us = (ushort*)&raw;
        #pragma unroll
        for (int k=0;k<8;k++){
            float x = bf2f(us[k])*ga[k] + be[k];
            acc[k] += silu_f(x);
        }
    }
    float rc = (o1>o0) ? 1.f/(float)(o1-o0) : 0.f;
    ushort out[8];
    #pragma unroll
    for (int k=0;k<8;k++) out[k]=f2bf(acc[k]*rc);
    int u = vox>>10, v = (vox>>5)&31, w = vox&31;
    size_t pd = ((size_t)b*PVOL) + (size_t)(u+1)*PSLICE + (v+1)*PROW + (w+1)*CO + c8*8;
    *(uint4*)(P + pd) = *(uint4*)out;
}

// ---------------- MFMA conv3d: padded bf16 volume -> raw bf16 (unpadded) + GN stats ----------------
__global__ __launch_bounds__(256) void k_conv_mfma(const __hip_bfloat16* __restrict__ P,
                        const short* __restrict__ wpack,
                        __hip_bfloat16* __restrict__ outv, float* __restrict__ stats){
    __shared__ __align__(16) char lds[9*PR*CO*2];   // 9 rows * 34 vox * 64ch bf16 = 39168 B
    int t = threadIdx.x;
    int blk = blockIdx.x;                 // (b*32+u)*32+v
    int b = blk >> 10;
    int u = (blk >> 5) & 31;
    int v = blk & 31;

    // ---- stage 9 padded rows into LDS with XOR swizzle (T2) ----
    const ushort* Pp = (const ushort*)P;
    for (int i = t; i < 9*272; i += 256){           // 272 chunks of 16B per row
        int r = i / 272;
        int chunk = i - r*272;
        size_t src = (size_t)b*PVOL + (size_t)(u + r/3)*PSLICE + (size_t)(v + r%3)*PROW + (size_t)chunk*8;
        uint4 val = *(const uint4*)(Pp + src);
        int vx = chunk >> 3;
        int colb = (chunk & 7) << 4;
        int dst = r*4352 + vx*128 + (colb ^ ((vx&7)<<4));
        *(uint4*)(lds + dst) = val;
    }
    __syncthreads();

    int l  = t & 63;
    int nt = t >> 6;                      // wave id = N-tile (16 oc)
    int lm = l & 15;
    int lk = l >> 4;
    int colb_base = lk*16;

    f32x4 acc0 = {0.f,0.f,0.f,0.f};
    f32x4 acc1 = {0.f,0.f,0.f,0.f};

    const short* wp = wpack + ((size_t)nt*64 + l)*8;   // [t][kc][nt][lane][8]
    for (int tap = 0; tap < 27; tap++){
        int r  = tap/3;
        int dx = tap - r*3;
        #pragma unroll
        for (int kc = 0; kc < 2; kc++){
            short8 bw = *(const short8*)(wp + ((size_t)(tap*2 + kc))*2048);
            int colb = colb_base + kc*64;
            int vx0 = lm + dx;
            int a0 = r*4352 + vx0*128 + (colb ^ ((vx0&7)<<4));
            int vx1 = vx0 + 16;
            int a1 = r*4352 + vx1*128 + (colb ^ ((vx1&7)<<4));
            short8 av0 = *(const short8*)(lds + a0);
            short8 av1 = *(const short8*)(lds + a1);
            acc0 = __builtin_amdgcn_mfma_f32_16x16x32_bf16(av0, bw, acc0, 0, 0, 0);
            acc1 = __builtin_amdgcn_mfma_f32_16x16x32_bf16(av1, bw, acc1, 0, 0, 0);
        }
    }

    // ---- store raw bf16 + GN stats ----
    int oc = nt*16 + lm;
    ushort* ob = (ushort*)outv;
    float s = 0.f, q = 0.f;
    #pragma unroll
    for (int j=0;j<4;j++){
        float v0 = acc0[j], v1 = acc1[j];
        s += v0 + v1; q += v0*v0 + v1*v1;
        int m = lk*4 + j;
        ob[((size_t)(blk*32 + m))*CO + oc]      = f2bf(v0);
        ob[((size_t)(blk*32 + 16 + m))*CO + oc] = f2bf(v1);
    }
    #pragma unroll
    for (int off : {1,2,4,16,32}){ s += __shfl_xor(s, off); q += __shfl_xor(q, off); }
    if (lk==0 && (lm&7)==0){
        int g = 2*nt + (lm>>3);
        atomicAdd(&stats[(b*GRP+g)*2],   s);
        atomicAdd(&stats[(b*GRP+g)*2+1], q);
    }
}

// ---------------- GN finalize + SiLU + cast into padded bf16 volume ----------------
__global__ __launch_bounds__(256) void k_gnfin_cast(const __hip_bfloat16* __restrict__ raw, const float* __restrict__ stats,
                        const float* __restrict__ gamma, const float* __restrict__ beta,
                        __hip_bfloat16* __restrict__ P){
    int i = blockIdx.x*256 + threadIdx.x;
    int c8 = i & 7;
    int vox = (i>>3) & (NVOX-1);
    int b = i >> 18;
    float s = stats[(b*GRP+c8)*2], qq = stats[(b*GRP+c8)*2+1];
    float m = s/GN_CNT;
    float inv = rsqrtf(qq/GN_CNT - m*m + 1e-5f);
    uint4 rv = *(const uint4*)((const ushort*)raw + ((size_t)i)*8);
    ushort* us = (ushort*)&rv;
    ushort out[8];
    #pragma unroll
    for (int j=0;j<8;j++){
        int c = c8*8+j;
        float x = (bf2f(us[j]) - m)*inv*gamma[c] + beta[c];
        out[j] = f2bf(silu_f(x));
    }
    int u = vox>>10, v = (vox>>5)&31, w = vox&31;
    size_t pd = ((size_t)b*PVOL) + (size_t)(u+1)*PSLICE + (v+1)*PROW + (w+1)*CO + c8*8;
    *(uint4*)((ushort*)P + pd) = *(uint4*)out;
}

// ---------------- GN finalize + SiLU, bf16 in place ----------------
__global__ __launch_bounds__(256) void k_gnfin_b16(__hip_bfloat16* __restrict__ raw, const float* __restrict__ stats,
                        const float* __restrict__ gamma, const float* __restrict__ beta){
    int i = blockIdx.x*256 + threadIdx.x;
    int c8 = i & 7;
    int b = i >> 18;
    float s = stats[(b*GRP+c8)*2], qq = stats[(b*GRP+c8)*2+1];
    float m = s/GN_CNT;
    float inv = rsqrtf(qq/GN_CNT - m*m + 1e-5f);
    uint4 rv = *(const uint4*)((const ushort*)raw + ((size_t)i)*8);
    ushort* us = (ushort*)&rv;
    ushort out[8];
    #pragma unroll
    for (int j=0;j<8;j++){
        int c = c8*8+j;
        float x = (bf2f(us[j]) - m)*inv*gamma[c] + beta[c];
        out[j] = f2bf(silu_f(x));
    }
    *(uint4*)((ushort*)raw + ((size_t)i)*8) = *(uint4*)out;
}

// ---------------- devoxelize (bf16 gather) + fuse conv1x1 (pre-GN, bf16 out) + stats ----------------
__global__ __launch_bounds__(256) void k_devox_fuse(const __hip_bfloat16* __restrict__ vox, const float* __restrict__ coords,
                             const float* __restrict__ vmm, const float* __restrict__ wf,
                             ushort* __restrict__ obuf, float* __restrict__ stats){
    __shared__ float wl[CO*CO];
    __shared__ float sred[GRP*2];
    int t = threadIdx.x;
    for (int i=t;i<CO*CO;i+=256) wl[i]=wf[i];
    if (t<GRP*2) sred[t]=0.f;
    __syncthreads();
    int p = blockIdx.x*256+t;
    int b = p>>15, n = p&(NP-1);
    const float* cp = coords + (size_t)(b*NP+n)*3;
    float fr[3]; int x0[3];
    #pragma unroll
    for(int d=0;d<3;d++){
        float vmin=vmm[b*6+d], vmax=vmm[b*6+3+d];
        float nr = (cp[d]-vmin)/fmaxf(vmax-vmin,1e-8f)*(RR-1);
        nr = fminf(fmaxf(nr,0.f),(float)(RR-1));
        float fl = floorf(nr);
        x0[d]=(int)fl; fr[d]=nr-fl;
    }
    float dev[CO];
    #pragma unroll
    for(int c=0;c<CO;c++) dev[c]=0.f;
    #pragma unroll
    for (int k=0;k<8;k++){
        int d0=(k>>2)&1, d1=(k>>1)&1, d2=k&1;
        int i0=min(x0[0]+d0,RR-1), i1=min(x0[1]+d1,RR-1), i2=min(x0[2]+d2,RR-1);
        float w = (d0?fr[0]:1.f-fr[0])*(d1?fr[1]:1.f-fr[1])*(d2?fr[2]:1.f-fr[2]);
        const ushort* vp = (const ushort*)vox + ((size_t)(b*NVOX) + (i0*RR+i1)*RR+i2)*CO;
        #pragma unroll
        for (int cc=0; cc<8; cc++){
            uint4 raw = *(const uint4*)(vp + cc*8);
            ushort* us = (ushort*)&raw;
            #pragma unroll
            for (int j=0;j<8;j++) dev[cc*8+j] += w * bf2f(us[j]);
        }
    }
    ushort* op = obuf + (size_t)p*CO;
    for (int og=0;og<GRP;og++){
        float gs=0.f,gq=0.f;
        ushort vals[8];
        #pragma unroll
        for(int j=0;j<CPG;j++){
            int o=og*CPG+j;
            float acc=0.f;
            #pragma unroll
            for(int c=0;c<CO;c++) acc+=wl[o*CO+c]*dev[c];
            vals[j]=f2bf(acc); gs+=acc; gq+=acc*acc;
        }
        *(uint4*)(op+og*CPG) = *(uint4*)vals;
        #pragma unroll
        for(int off=32;off>=1;off>>=1){ gs+=__shfl_down(gs,off); gq+=__shfl_down(gq,off); }
        if((t&63)==0){ atomicAdd(&sred[og*2],gs); atomicAdd(&sred[og*2+1],gq); }
    }
    __syncthreads();
    if(t<GRP){ atomicAdd(&stats[(b*GRP+t)*2], sred[t*2]); atomicAdd(&stats[(b*GRP+t)*2+1], sred[t*2+1]); }
}

// ---------------- final: GN+SiLU + skip conv + AdaIN, write (B,C,N) ----------------
__global__ __launch_bounds__(256) void k_final(const ushort* __restrict__ obuf, const float* __restrict__ stats,
                        const float* __restrict__ gamma, const float* __restrict__ beta,
                        const float* __restrict__ feats, const float* __restrict__ wskip,
                        const float* __restrict__ ada_s, const float* __restrict__ ada_b,
                        float* __restrict__ out){
    __shared__ float wl[CO*CIN];
    int t=threadIdx.x;
    for(int i=t;i<CO*CIN;i+=256) wl[i]=wskip[i];
    __syncthreads();
    int p = blockIdx.x*256+t;
    int b=p>>15, n=p&(NP-1);
    float mean[GRP], inv[GRP];
    #pragma unroll
    for(int g=0;g<GRP;g++){
        float s=stats[(b*GRP+g)*2], q=stats[(b*GRP+g)*2+1];
        float m=s/GN_CNT;
        float v=q/GN_CNT-m*m;
        mean[g]=m; inv[g]=rsqrtf(v+1e-5f);
    }
    float f[CIN];
    const float* fp=feats + (size_t)b*CIN*NP + n;
    #pragma unroll
    for(int c=0;c<CIN;c++) f[c]=fp[(size_t)c*NP];
    float iv[CO];
    const ushort* ip = obuf + (size_t)p*CO;
    #pragma unroll
    for (int cc=0;cc<8;cc++){
        uint4 raw = *(const uint4*)(ip + cc*8);
        ushort* us = (ushort*)&raw;
        #pragma unroll
        for (int j=0;j<8;j++) iv[cc*8+j]=bf2f(us[j]);
    }
    float* op = out + (size_t)b*CO*NP + n;
    for(int o=0;o<CO;o++){
        int g=o>>3;
        float u=(iv[o]-mean[g])*inv[g]*gamma[o]+beta[o];
        u=silu_f(u);
        float sk=0.f;
        #pragma unroll
        for(int c=0;c<CIN;c++) sk+=wl[o*CIN+c]*f[c];
        float s=ada_s[b*CO+o], bb=ada_b[b*CO+o];
        op[(size_t)o*NP] = (u+sk)*(1.f+s)+bb;
    }
}

extern "C" void kernel_launch(void* const* d_in, const int* in_sizes, int n_in,
                              void* d_out, int out_size, void* d_ws, size_t ws_size,
                              hipStream_t stream){
    const float* feats =(const float*)d_in[0];
    const float* coords=(const float*)d_in[1];
    const float* style =(const float*)d_in[2];
    const float* w_pin =(const float*)d_in[3];
    const float* g_pin =(const float*)d_in[4];
    const float* b_pin =(const float*)d_in[5];
    const float* w_v1  =(const float*)d_in[6];
    const float* g_v1  =(const float*)d_in[7];
    const float* b_v1  =(const float*)d_in[8];
    const float* w_v2  =(const float*)d_in[9];
    const float* g_v2  =(const float*)d_in[10];
    const float* b_v2  =(const float*)d_in[11];
    const float* w_fuse=(const float*)d_in[12];
    const float* g_f   =(const float*)d_in[13];
    const float* b_f   =(const float*)d_in[14];
    const float* w_skip=(const float*)d_in[15];
    const float* w_as  =(const float*)d_in[16];
    const float* b_as  =(const float*)d_in[17];
    const float* w_ab  =(const float*)d_in[18];
    const float* b_ab  =(const float*)d_in[19];
    float* out=(float*)d_out;
    char* ws =(char*)d_ws;

    // workspace layout (bytes)
    ushort* ybuf  = (ushort*)ws;                            // 16.7 MB (aliased later by obuf)
    ushort* Pvol  = (ushort*)(ws + 16777216);               // 20.1 MB
    ushort* raw   = (ushort*)(ws + 16777216 + 20123648);    // 16.7 MB
    char*   small = ws + 16777216 + 20123648 + 16777216;
    float* stats  = (float*)small;                          // 256 floats
    float* vmm    = stats + 256;                            // 24
    float* ada_s  = vmm + 24;                               // 256
    float* ada_b  = ada_s + RB*CO;                          // 256
    short* wp1    = (short*)(ada_b + RB*CO);                // 110592 shorts
    short* wp2    = wp1 + 27*2*4*64*8;                      // 110592 shorts
    int*   pid    = (int*)(wp2 + 27*2*4*64*8);              // RB*NP
    int*   cnt    = pid + RB*NP;                            // RB*NVOX
    int*   offs   = cnt + RB*NVOX;                          // RB*NVOX
    int*   cursor = offs + RB*NVOX;                         // RB*NVOX
    int*   order  = cursor + RB*NVOX;                       // RB*NP
    ushort* obuf  = ybuf;                                   // reuse after gather

    float* st0 = stats;
    float* st1 = stats + 64;
    float* st2 = stats + 128;
    float* st3 = stats + 192;

    hipMemsetAsync(stats, 0, 256*sizeof(float), stream);
    hipMemsetAsync(cnt, 0, (size_t)RB*NVOX*sizeof(int), stream);
    hipMemsetAsync(Pvol, 0, (size_t)RB*PVOL*sizeof(ushort), stream);

    k_wpack<<<54,256,0,stream>>>(w_v1, wp1);
    k_wpack<<<54,256,0,stream>>>(w_v2, wp2);
    k_adain<<<1,256,0,stream>>>(style,w_as,b_as,w_ab,b_ab,ada_s,ada_b);
    k_minmax<<<RB,256,0,stream>>>(coords,vmm);

    k_pin<<<RB*NP/256,256,0,stream>>>(feats,w_pin,ybuf,st0);
    k_count<<<RB*NP/256,256,0,stream>>>(coords,vmm,pid,cnt);
    k_scan<<<RB,1024,0,stream>>>(cnt,offs,cursor);
    k_fill<<<RB*NP/256,256,0,stream>>>(pid,cursor,order);
    k_gather_pad<<<RB*NVOX*8/256,256,0,stream>>>(ybuf,offs,order,st0,g_pin,b_pin,Pvol);

    k_conv_mfma<<<RB*RR*RR,256,0,stream>>>((const __hip_bfloat16*)Pvol, wp1, (__hip_bfloat16*)raw, st1);
    k_gnfin_cast<<<RB*NVOX*8/256,256,0,stream>>>((const __hip_bfloat16*)raw, st1, g_v1, b_v1, (__hip_bfloat16*)Pvol);
    k_conv_mfma<<<RB*RR*RR,256,0,stream>>>((const __hip_bfloat16*)Pvol, wp2, (__hip_bfloat16*)raw, st2);
    k_gnfin_b16<<<RB*NVOX*8/256,256,0,stream>>>((__hip_bfloat16*)raw, st2, g_v2, b_v2);

    k_devox_fuse<<<RB*NP/256,256,0,stream>>>((const __hip_bfloat16*)raw, coords, vmm, w_fuse, obuf, st3);
    k_final<<<RB*NP/256,256,0,stream>>>(obuf, st3, g_f, b_f, feats, w_skip, ada_s, ada_b, out);
}

// Round 4
// 589.864 us; speedup vs baseline: 6.3722x; 1.4759x over previous
//
#include <hip/hip_runtime.h>
#include <hip/hip_bf16.h>
#include <math.h>

#define RR   32
#define RB   4
#define CIN  32
#define CO   64
#define NP   32768
#define SD   256
#define NVOX (RR*RR*RR)       // 32768
#define GRP  8
#define CPG  8
#define GN_CNT 262144.0f      // 8 ch * 32768 vox per group
#define PR   34               // padded resolution
#define PSLICE (PR*PR*CO)     // 73984   (U stride)
#define PROW   (PR*CO)        // 2176    (V stride)
#define PVOL   ((size_t)PR*PR*PR*CO)   // per-batch padded elems 2,515,456

typedef __attribute__((ext_vector_type(8))) short short8;
typedef __attribute__((ext_vector_type(4))) float f32x4;

__device__ inline float silu_f(float x){ return x / (1.f + __expf(-x)); }
__device__ inline float bf2f(ushort u){ uint v = ((uint)u)<<16; return *(float*)&v; }
__device__ inline ushort f2bf(float x){ __hip_bfloat16 h = __float2bfloat16(x); return *(ushort*)&h; }

// ---------------- weight pack: (O,I,3,3,3) fp32 -> bf16 [t][kc][nt][lane][8] ----------------
__global__ void k_wpack(const float* __restrict__ w, short* __restrict__ wp){
    int i = blockIdx.x*256 + threadIdx.x;       // 27*2*4*64 = 13824
    if (i >= 27*2*4*64) return;
    int l  = i & 63;
    int nt = (i>>6) & 3;
    int kc = (i>>8) & 1;
    int t  = i>>9;
    int oc = nt*16 + (l&15);
    int cib = kc*32 + (l>>4)*8;
    ushort out[8];
    #pragma unroll
    for (int j=0;j<8;j++) out[j] = f2bf(w[((oc*CO + cib + j))*27 + t]);
    *(uint4*)(wp + (size_t)i*8) = *(uint4*)out;
}

// ---------------- AdaIN params ----------------
__global__ void k_adain(const float* __restrict__ style, const float* __restrict__ w_as,
                        const float* __restrict__ b_as, const float* __restrict__ w_ab,
                        const float* __restrict__ b_ab, float* __restrict__ sout,
                        float* __restrict__ bout){
    int t = threadIdx.x;            // 256 = B*CO
    int b = t >> 6, o = t & 63;
    const float* st = style + b*SD;
    float accs = b_as[o], accb = b_ab[o];
    for (int k=0;k<SD;k++){ float sv = st[k]; accs += sv*w_as[o*SD+k]; accb += sv*w_ab[o*SD+k]; }
    sout[t]=accs; bout[t]=accb;
}

// ---------------- per-batch coord min/max ----------------
__global__ void k_minmax(const float* __restrict__ coords, float* __restrict__ vmm){
    int b = blockIdx.x; int t = threadIdx.x;
    float mn[3]={1e30f,1e30f,1e30f}, mx[3]={-1e30f,-1e30f,-1e30f};
    const float* cp = coords + (size_t)b*NP*3;
    for (int n=t;n<NP;n+=256){
        #pragma unroll
        for(int d=0;d<3;d++){ float v = cp[n*3+d]; mn[d]=fminf(mn[d],v); mx[d]=fmaxf(mx[d],v);}
    }
    __shared__ float smn[256][3], smx[256][3];
    #pragma unroll
    for(int d=0;d<3;d++){ smn[t][d]=mn[d]; smx[t][d]=mx[d]; }
    __syncthreads();
    for(int s=128;s>0;s>>=1){
        if(t<s){
            #pragma unroll
            for(int d=0;d<3;d++){
                smn[t][d]=fminf(smn[t][d],smn[t+s][d]);
                smx[t][d]=fmaxf(smx[t][d],smx[t+s][d]);
            }
        }
        __syncthreads();
    }
    if(t<3){ vmm[b*6+t]=smn[0][t]; vmm[b*6+3+t]=smx[0][t]; }
}

// ---------------- point_in conv1x1 (pre-GN, bf16 out) + GN stats ----------------
__global__ __launch_bounds__(256) void k_pin(const float* __restrict__ feats, const float* __restrict__ w_pin,
                      ushort* __restrict__ ybuf, float* __restrict__ stats){
    __shared__ float wl[CO*CIN];
    __shared__ float sred[GRP*2];
    int t = threadIdx.x;
    for (int i=t;i<CO*CIN;i+=256) wl[i]=w_pin[i];
    if (t<GRP*2) sred[t]=0.f;
    __syncthreads();
    int p = blockIdx.x*256 + t;
    int b = p >> 15;
    int n = p & (NP-1);
    const float* fp = feats + (size_t)b*CIN*NP + n;
    float f[CIN];
    #pragma unroll
    for(int c=0;c<CIN;c++) f[c]=fp[(size_t)c*NP];
    ushort* yo = ybuf + (size_t)p*CO;
    for (int og=0;og<GRP;og++){
        float gs=0.f, gq=0.f;
        ushort vals[8];
        #pragma unroll
        for (int j=0;j<CPG;j++){
            int o = og*CPG + j;
            float acc=0.f;
            #pragma unroll
            for(int c=0;c<CIN;c++) acc += wl[o*CIN+c]*f[c];
            vals[j]=f2bf(acc); gs+=acc; gq+=acc*acc;
        }
        *(uint4*)(yo + og*CPG) = *(uint4*)vals;
        #pragma unroll
        for (int off=32; off>=1; off>>=1){ gs += __shfl_down(gs, off); gq += __shfl_down(gq, off); }
        if ((t&63)==0){ atomicAdd(&sred[og*2], gs); atomicAdd(&sred[og*2+1], gq); }
    }
    __syncthreads();
    if (t<GRP){ atomicAdd(&stats[(b*GRP+t)*2], sred[t*2]); atomicAdd(&stats[(b*GRP+t)*2+1], sred[t*2+1]); }
}

// ---------------- voxel id per point + per-voxel count ----------------
__global__ __launch_bounds__(256) void k_count(const float* __restrict__ coords, const float* __restrict__ vmm,
                        int* __restrict__ pid, int* __restrict__ cnt){
    int p = blockIdx.x*256 + threadIdx.x;
    int b = p >> 15, n = p & (NP-1);
    const float* cp = coords + (size_t)(b*NP + n)*3;
    int id[3];
    #pragma unroll
    for(int d=0;d<3;d++){
        float vmin = vmm[b*6+d], vmax = vmm[b*6+3+d];
        float nr = (cp[d]-vmin)/fmaxf(vmax-vmin,1e-8f)*(RR-1);
        int ii = (int)rintf(nr);
        id[d] = min(max(ii,0),RR-1);
    }
    int flat = (id[0]*RR + id[1])*RR + id[2];
    pid[p] = flat;
    atomicAdd(&cnt[(b<<15)+flat], 1);
}

// ---------------- per-batch exclusive scan of 32768 counts ----------------
__global__ __launch_bounds__(1024) void k_scan(const int* __restrict__ cnt, int* __restrict__ offs,
                        int* __restrict__ cursor){
    int b = blockIdx.x, t = threadIdx.x;
    const int* c = cnt + (b<<15);
    int base = t*32;
    int pref[32];
    int s = 0;
    #pragma unroll
    for (int k4=0;k4<8;k4++){
        int4 q = *(const int4*)(c + base + k4*4);
        pref[k4*4+0]=s; s+=q.x;
        pref[k4*4+1]=s; s+=q.y;
        pref[k4*4+2]=s; s+=q.z;
        pref[k4*4+3]=s; s+=q.w;
    }
    int lane = t & 63, w = t >> 6;
    int inc = s;
    #pragma unroll
    for (int off=1; off<64; off<<=1){ int u = __shfl_up(inc, off); if (lane>=off) inc += u; }
    __shared__ int wsum[16];
    if (lane==63) wsum[w]=inc;
    __syncthreads();
    int wexcl=0;
    for (int i=0;i<w;i++) wexcl += wsum[i];
    int texcl = wexcl + inc - s;
    int* o = offs + (b<<15) + base;
    int* cu = cursor + (b<<15) + base;
    #pragma unroll
    for (int k=0;k<32;k++){ int v = texcl + pref[k]; o[k]=v; cu[k]=v; }
}

// ---------------- place point indices into CSR order ----------------
__global__ __launch_bounds__(256) void k_fill(const int* __restrict__ pid, int* __restrict__ cursor,
                       int* __restrict__ order){
    int p = blockIdx.x*256 + threadIdx.x;
    int b = p >> 15, n = p & (NP-1);
    int v = pid[p];
    int slot = atomicAdd(&cursor[(b<<15)+v], 1);
    order[(b<<15)+slot] = n;
}

// ---------------- gather per voxel: GN+SiLU(y) average -> padded bf16 volume ----------------
__global__ __launch_bounds__(256) void k_gather_pad(const ushort* __restrict__ ybuf, const int* __restrict__ offs,
                             const int* __restrict__ order, const float* __restrict__ stats,
                             const float* __restrict__ gamma, const float* __restrict__ beta,
                             ushort* __restrict__ P){
    int i = blockIdx.x*256 + threadIdx.x;   // RB*NVOX*8
    int c8 = i & 7;
    int vox = (i>>3) & (NVOX-1);
    int b = i >> 18;
    float s = stats[(b*GRP+c8)*2], qq = stats[(b*GRP+c8)*2+1];
    float m = s/GN_CNT;
    float inv = rsqrtf(qq/GN_CNT - m*m + 1e-5f);
    float ga[8], be[8];
    #pragma unroll
    for (int k=0;k<8;k++){ ga[k]=gamma[c8*8+k]*inv; be[k]=beta[c8*8+k]-m*ga[k]; }
    int o0 = offs[(b<<15)+vox];
    int o1 = (vox==NVOX-1) ? NP : offs[(b<<15)+vox+1];
    float acc[8];
    #pragma unroll
    for (int k=0;k<8;k++) acc[k]=0.f;
    for (int j=o0; j<o1; j++){
        int n = order[(b<<15)+j];
        uint4 raw = *(const uint4*)(ybuf + ((size_t)((b<<15)+n))*CO + c8*8);
        ushort* us = (ushort*)&raw;
        #pragma unroll
        for (int k=0;k<8;k++){
            float x = bf2f(us[k])*ga[k] + be[k];
            acc[k] += silu_f(x);
        }
    }
    float rc = (o1>o0) ? 1.f/(float)(o1-o0) : 0.f;
    ushort out[8];
    #pragma unroll
    for (int k=0;k<8;k++) out[k]=f2bf(acc[k]*rc);
    int u = vox>>10, v = (vox>>5)&31, w = vox&31;
    size_t pd = ((size_t)b*PVOL) + (size_t)(u+1)*PSLICE + (v+1)*PROW + (w+1)*CO + c8*8;
    *(uint4*)(P + pd) = *(uint4*)out;
}

// ---------------- MFMA conv3d: (u, 4 v-rows) per 512-thread block ----------------
// 8 waves = 2 v-groups x 4 oc-tiles; 4 acc tiles/wave; 18 staged rows (78 KB LDS)
__global__ __launch_bounds__(512, 4) void k_conv_mfma(const __hip_bfloat16* __restrict__ P,
                        const short* __restrict__ wpack,
                        __hip_bfloat16* __restrict__ outv, float* __restrict__ stats){
    __shared__ __align__(16) char lds[18*PR*CO*2];   // 18 rows * 34 vox * 64ch bf16 = 78336 B
    int t = threadIdx.x;
    int blk = blockIdx.x;                 // ((b*32+u)*8 + vt)
    int vt = blk & 7;
    int u  = (blk >> 3) & 31;
    int b  = blk >> 8;
    int v0 = vt*4;                        // first output v of this block

    // ---- stage 18 padded rows (u..u+2, v0..v0+5) into LDS with XOR swizzle ----
    const ushort* Pp = (const ushort*)P;
    for (int i = t; i < 18*272; i += 512){
        int r = i / 272;                  // 0..17
        int chunk = i - r*272;
        int ur = r / 6, vr = r - ur*6;
        size_t src = (size_t)b*PVOL + (size_t)(u+ur)*PSLICE + (size_t)(v0+vr)*PROW + (size_t)chunk*8;
        uint4 val = *(const uint4*)(Pp + src);
        int vx = chunk >> 3;
        int colb = (chunk & 7) << 4;
        int dst = r*4352 + vx*128 + (colb ^ ((vx&7)<<4));
        *(uint4*)(lds + dst) = val;
    }
    __syncthreads();

    int l  = t & 63;
    int wv = t >> 6;                      // 0..7
    int nt = wv & 3;                      // oc tile (16 oc)
    int mg = wv >> 2;                     // v-group: rows {2mg, 2mg+1}
    int lm = l & 15;
    int lk = l >> 4;
    int colb_base = lk*16;

    f32x4 acc[2][2] = {};                 // [vl][wh]

    const short* wp = wpack + ((size_t)nt*64 + l)*8;   // [t][kc][nt][lane][8]
    for (int dz = 0; dz < 3; dz++){
      for (int dy = 0; dy < 3; dy++){
        int row0 = dz*6 + 2*mg + dy;      // LDS row for vl=0 (row0+1 for vl=1)
        int rb0 = row0*4352;
        #pragma unroll
        for (int dx = 0; dx < 3; dx++){
          int tap = (dz*3 + dy)*3 + dx;
          int vxa = lm + dx;
          int sw  = (vxa & 7) << 4;
          int base0 = rb0 + vxa*128;
          #pragma unroll
          for (int kc = 0; kc < 2; kc++){
            short8 bw = *(const short8*)(wp + ((size_t)(tap*2 + kc))*2048);
            int cb = (colb_base + kc*64) ^ sw;
            short8 a00 = *(const short8*)(lds + base0 + cb);
            short8 a01 = *(const short8*)(lds + base0 + 2048 + cb);        // wh=1 (+16 vox)
            short8 a10 = *(const short8*)(lds + base0 + 4352 + cb);        // vl=1
            short8 a11 = *(const short8*)(lds + base0 + 4352 + 2048 + cb);
            acc[0][0] = __builtin_amdgcn_mfma_f32_16x16x32_bf16(a00, bw, acc[0][0], 0, 0, 0);
            acc[0][1] = __builtin_amdgcn_mfma_f32_16x16x32_bf16(a01, bw, acc[0][1], 0, 0, 0);
            acc[1][0] = __builtin_amdgcn_mfma_f32_16x16x32_bf16(a10, bw, acc[1][0], 0, 0, 0);
            acc[1][1] = __builtin_amdgcn_mfma_f32_16x16x32_bf16(a11, bw, acc[1][1], 0, 0, 0);
          }
        }
      }
    }

    // ---- store raw bf16 + GN stats ----
    int oc = nt*16 + lm;
    ushort* ob = (ushort*)outv;
    float s = 0.f, q = 0.f;
    size_t vbase = ((size_t)(b*32 + u)*32 + v0 + 2*mg);    // voxel-row index
    #pragma unroll
    for (int vl = 0; vl < 2; vl++){
      #pragma unroll
      for (int wh = 0; wh < 2; wh++){
        #pragma unroll
        for (int j = 0; j < 4; j++){
          float vv = acc[vl][wh][j];
          s += vv; q += vv*vv;
          int w = wh*16 + lk*4 + j;
          ob[((vbase + vl)*32 + w)*CO + oc] = f2bf(vv);
        }
      }
    }
    #pragma unroll
    for (int off : {1,2,4,16,32}){ s += __shfl_xor(s, off); q += __shfl_xor(q, off); }
    if (lk==0 && (lm&7)==0){
        int g = 2*nt + (lm>>3);
        atomicAdd(&stats[(b*GRP+g)*2],   s);
        atomicAdd(&stats[(b*GRP+g)*2+1], q);
    }
}

// ---------------- GN finalize + SiLU + cast into padded bf16 volume ----------------
__global__ __launch_bounds__(256) void k_gnfin_cast(const __hip_bfloat16* __restrict__ raw, const float* __restrict__ stats,
                        const float* __restrict__ gamma, const float* __restrict__ beta,
                        __hip_bfloat16* __restrict__ P){
    int i = blockIdx.x*256 + threadIdx.x;
    int c8 = i & 7;
    int vox = (i>>3) & (NVOX-1);
    int b = i >> 18;
    float s = stats[(b*GRP+c8)*2], qq = stats[(b*GRP+c8)*2+1];
    float m = s/GN_CNT;
    float inv = rsqrtf(qq/GN_CNT - m*m + 1e-5f);
    uint4 rv = *(const uint4*)((const ushort*)raw + ((size_t)i)*8);
    ushort* us = (ushort*)&rv;
    ushort out[8];
    #pragma unroll
    for (int j=0;j<8;j++){
        int c = c8*8+j;
        float x = (bf2f(us[j]) - m)*inv*gamma[c] + beta[c];
        out[j] = f2bf(silu_f(x));
    }
    int u = vox>>10, v = (vox>>5)&31, w = vox&31;
    size_t pd = ((size_t)b*PVOL) + (size_t)(u+1)*PSLICE + (v+1)*PROW + (w+1)*CO + c8*8;
    *(uint4*)((ushort*)P + pd) = *(uint4*)out;
}

// ---------------- GN finalize + SiLU, bf16 in place ----------------
__global__ __launch_bounds__(256) void k_gnfin_b16(__hip_bfloat16* __restrict__ raw, const float* __restrict__ stats,
                        const float* __restrict__ gamma, const float* __restrict__ beta){
    int i = blockIdx.x*256 + threadIdx.x;
    int c8 = i & 7;
    int b = i >> 18;
    float s = stats[(b*GRP+c8)*2], qq = stats[(b*GRP+c8)*2+1];
    float m = s/GN_CNT;
    float inv = rsqrtf(qq/GN_CNT - m*m + 1e-5f);
    uint4 rv = *(const uint4*)((const ushort*)raw + ((size_t)i)*8);
    ushort* us = (ushort*)&rv;
    ushort out[8];
    #pragma unroll
    for (int j=0;j<8;j++){
        int c = c8*8+j;
        float x = (bf2f(us[j]) - m)*inv*gamma[c] + beta[c];
        out[j] = f2bf(silu_f(x));
    }
    *(uint4*)((ushort*)raw + ((size_t)i)*8) = *(uint4*)out;
}

// ---------------- devoxelize (bf16 gather) + fuse conv1x1 (pre-GN, bf16 out) + stats ----------------
__global__ __launch_bounds__(256) void k_devox_fuse(const __hip_bfloat16* __restrict__ vox, const float* __restrict__ coords,
                             const float* __restrict__ vmm, const float* __restrict__ wf,
                             ushort* __restrict__ obuf, float* __restrict__ stats){
    __shared__ float wl[CO*CO];
    __shared__ float sred[GRP*2];
    int t = threadIdx.x;
    for (int i=t;i<CO*CO;i+=256) wl[i]=wf[i];
    if (t<GRP*2) sred[t]=0.f;
    __syncthreads();
    int p = blockIdx.x*256+t;
    int b = p>>15, n = p&(NP-1);
    const float* cp = coords + (size_t)(b*NP+n)*3;
    float fr[3]; int x0[3];
    #pragma unroll
    for(int d=0;d<3;d++){
        float vmin=vmm[b*6+d], vmax=vmm[b*6+3+d];
        float nr = (cp[d]-vmin)/fmaxf(vmax-vmin,1e-8f)*(RR-1);
        nr = fminf(fmaxf(nr,0.f),(float)(RR-1));
        float fl = floorf(nr);
        x0[d]=(int)fl; fr[d]=nr-fl;
    }
    float dev[CO];
    #pragma unroll
    for(int c=0;c<CO;c++) dev[c]=0.f;
    #pragma unroll
    for (int k=0;k<8;k++){
        int d0=(k>>2)&1, d1=(k>>1)&1, d2=k&1;
        int i0=min(x0[0]+d0,RR-1), i1=min(x0[1]+d1,RR-1), i2=min(x0[2]+d2,RR-1);
        float w = (d0?fr[0]:1.f-fr[0])*(d1?fr[1]:1.f-fr[1])*(d2?fr[2]:1.f-fr[2]);
        const ushort* vp = (const ushort*)vox + ((size_t)(b*NVOX) + (i0*RR+i1)*RR+i2)*CO;
        #pragma unroll
        for (int cc=0; cc<8; cc++){
            uint4 raw = *(const uint4*)(vp + cc*8);
            ushort* us = (ushort*)&raw;
            #pragma unroll
            for (int j=0;j<8;j++) dev[cc*8+j] += w * bf2f(us[j]);
        }
    }
    ushort* op = obuf + (size_t)p*CO;
    for (int og=0;og<GRP;og++){
        float gs=0.f,gq=0.f;
        ushort vals[8];
        #pragma unroll
        for(int j=0;j<CPG;j++){
            int o=og*CPG+j;
            float acc=0.f;
            #pragma unroll
            for(int c=0;c<CO;c++) acc+=wl[o*CO+c]*dev[c];
            vals[j]=f2bf(acc); gs+=acc; gq+=acc*acc;
        }
        *(uint4*)(op+og*CPG) = *(uint4*)vals;
        #pragma unroll
        for(int off=32;off>=1;off>>=1){ gs+=__shfl_down(gs,off); gq+=__shfl_down(gq,off); }
        if((t&63)==0){ atomicAdd(&sred[og*2],gs); atomicAdd(&sred[og*2+1],gq); }
    }
    __syncthreads();
    if(t<GRP){ atomicAdd(&stats[(b*GRP+t)*2], sred[t*2]); atomicAdd(&stats[(b*GRP+t)*2+1], sred[t*2+1]); }
}

// ---------------- final: GN+SiLU + skip conv + AdaIN, write (B,C,N) ----------------
__global__ __launch_bounds__(256) void k_final(const ushort* __restrict__ obuf, const float* __restrict__ stats,
                        const float* __restrict__ gamma, const float* __restrict__ beta,
                        const float* __restrict__ feats, const float* __restrict__ wskip,
                        const float* __restrict__ ada_s, const float* __restrict__ ada_b,
                        float* __restrict__ out){
    __shared__ float wl[CO*CIN];
    int t=threadIdx.x;
    for(int i=t;i<CO*CIN;i+=256) wl[i]=wskip[i];
    __syncthreads();
    int p = blockIdx.x*256+t;
    int b=p>>15, n=p&(NP-1);
    float mean[GRP], inv[GRP];
    #pragma unroll
    for(int g=0;g<GRP;g++){
        float s=stats[(b*GRP+g)*2], q=stats[(b*GRP+g)*2+1];
        float m=s/GN_CNT;
        float v=q/GN_CNT-m*m;
        mean[g]=m; inv[g]=rsqrtf(v+1e-5f);
    }
    float f[CIN];
    const float* fp=feats + (size_t)b*CIN*NP + n;
    #pragma unroll
    for(int c=0;c<CIN;c++) f[c]=fp[(size_t)c*NP];
    float iv[CO];
    const ushort* ip = obuf + (size_t)p*CO;
    #pragma unroll
    for (int cc=0;cc<8;cc++){
        uint4 raw = *(const uint4*)(ip + cc*8);
        ushort* us = (ushort*)&raw;
        #pragma unroll
        for (int j=0;j<8;j++) iv[cc*8+j]=bf2f(us[j]);
    }
    float* op = out + (size_t)b*CO*NP + n;
    for(int o=0;o<CO;o++){
        int g=o>>3;
        float u=(iv[o]-mean[g])*inv[g]*gamma[o]+beta[o];
        u=silu_f(u);
        float sk=0.f;
        #pragma unroll
        for(int c=0;c<CIN;c++) sk+=wl[o*CIN+c]*f[c];
        float s=ada_s[b*CO+o], bb=ada_b[b*CO+o];
        op[(size_t)o*NP] = (u+sk)*(1.f+s)+bb;
    }
}

extern "C" void kernel_launch(void* const* d_in, const int* in_sizes, int n_in,
                              void* d_out, int out_size, void* d_ws, size_t ws_size,
                              hipStream_t stream){
    const float* feats =(const float*)d_in[0];
    const float* coords=(const float*)d_in[1];
    const float* style =(const float*)d_in[2];
    const float* w_pin =(const float*)d_in[3];
    const float* g_pin =(const float*)d_in[4];
    const float* b_pin =(const float*)d_in[5];
    const float* w_v1  =(const float*)d_in[6];
    const float* g_v1  =(const float*)d_in[7];
    const float* b_v1  =(const float*)d_in[8];
    const float* w_v2  =(const float*)d_in[9];
    const float* g_v2  =(const float*)d_in[10];
    const float* b_v2  =(const float*)d_in[11];
    const float* w_fuse=(const float*)d_in[12];
    const float* g_f   =(const float*)d_in[13];
    const float* b_f   =(const float*)d_in[14];
    const float* w_skip=(const float*)d_in[15];
    const float* w_as  =(const float*)d_in[16];
    const float* b_as  =(const float*)d_in[17];
    const float* w_ab  =(const float*)d_in[18];
    const float* b_ab  =(const float*)d_in[19];
    float* out=(float*)d_out;
    char* ws =(char*)d_ws;

    // workspace layout (bytes)
    ushort* ybuf  = (ushort*)ws;                            // 16.7 MB (aliased later by obuf)
    ushort* Pvol  = (ushort*)(ws + 16777216);               // 20.1 MB
    ushort* raw   = (ushort*)(ws + 16777216 + 20123648);    // 16.7 MB
    char*   small = ws + 16777216 + 20123648 + 16777216;
    float* stats  = (float*)small;                          // 256 floats
    float* vmm    = stats + 256;                            // 24
    float* ada_s  = vmm + 24;                               // 256
    float* ada_b  = ada_s + RB*CO;                          // 256
    short* wp1    = (short*)(ada_b + RB*CO);                // 110592 shorts
    short* wp2    = wp1 + 27*2*4*64*8;                      // 110592 shorts
    int*   pid    = (int*)(wp2 + 27*2*4*64*8);              // RB*NP
    int*   cnt    = pid + RB*NP;                            // RB*NVOX
    int*   offs   = cnt + RB*NVOX;                          // RB*NVOX
    int*   cursor = offs + RB*NVOX;                         // RB*NVOX
    int*   order  = cursor + RB*NVOX;                       // RB*NP
    ushort* obuf  = ybuf;                                   // reuse after gather

    float* st0 = stats;
    float* st1 = stats + 64;
    float* st2 = stats + 128;
    float* st3 = stats + 192;

    hipMemsetAsync(stats, 0, 256*sizeof(float), stream);
    hipMemsetAsync(cnt, 0, (size_t)RB*NVOX*sizeof(int), stream);
    hipMemsetAsync(Pvol, 0, (size_t)RB*PVOL*sizeof(ushort), stream);

    k_wpack<<<54,256,0,stream>>>(w_v1, wp1);
    k_wpack<<<54,256,0,stream>>>(w_v2, wp2);
    k_adain<<<1,256,0,stream>>>(style,w_as,b_as,w_ab,b_ab,ada_s,ada_b);
    k_minmax<<<RB,256,0,stream>>>(coords,vmm);

    k_pin<<<RB*NP/256,256,0,stream>>>(feats,w_pin,ybuf,st0);
    k_count<<<RB*NP/256,256,0,stream>>>(coords,vmm,pid,cnt);
    k_scan<<<RB,1024,0,stream>>>(cnt,offs,cursor);
    k_fill<<<RB*NP/256,256,0,stream>>>(pid,cursor,order);
    k_gather_pad<<<RB*NVOX*8/256,256,0,stream>>>(ybuf,offs,order,st0,g_pin,b_pin,Pvol);

    k_conv_mfma<<<RB*RR*8,512,0,stream>>>((const __hip_bfloat16*)Pvol, wp1, (__hip_bfloat16*)raw, st1);
    k_gnfin_cast<<<RB*NVOX*8/256,256,0,stream>>>((const __hip_bfloat16*)raw, st1, g_v1, b_v1, (__hip_bfloat16*)Pvol);
    k_conv_mfma<<<RB*RR*8,512,0,stream>>>((const __hip_bfloat16*)Pvol, wp2, (__hip_bfloat16*)raw, st2);
    k_gnfin_b16<<<RB*NVOX*8/256,256,0,stream>>>((__hip_bfloat16*)raw, st2, g_v2, b_v2);

    k_devox_fuse<<<RB*NP/256,256,0,stream>>>((const __hip_bfloat16*)raw, coords, vmm, w_fuse, obuf, st3);
    k_final<<<RB*NP/256,256,0,stream>>>(obuf, st3, g_f, b_f, feats, w_skip, ada_s, ada_b, out);
}

// Round 5
// 584.697 us; speedup vs baseline: 6.4285x; 1.0088x over previous
//
#include <hip/hip_runtime.h>
#include <hip/hip_bf16.h>
#include <math.h>

#define RR   32
#define RB   4
#define CIN  32
#define CO   64
#define NP   32768
#define SD   256
#define NVOX (RR*RR*RR)       // 32768
#define GRP  8
#define CPG  8
#define GN_CNT 262144.0f      // 8 ch * 32768 vox per group
#define PR   34               // padded resolution
#define PSLICE (PR*PR*CO)     // 73984   (U stride)
#define PROW   (PR*CO)        // 2176    (V stride)
#define PVOL   ((size_t)PR*PR*PR*CO)   // per-batch padded elems 2,515,456

typedef __attribute__((ext_vector_type(8))) short short8;
typedef __attribute__((ext_vector_type(4))) float f32x4;
typedef __attribute__((ext_vector_type(16))) float f32x16;

__device__ inline float silu_f(float x){ return x / (1.f + __expf(-x)); }
__device__ inline float bf2f(ushort u){ uint v = ((uint)u)<<16; return *(float*)&v; }
__device__ inline ushort f2bf(float x){ __hip_bfloat16 h = __float2bfloat16(x); return *(ushort*)&h; }

// ---------------- weight pack: (O,I,3,3,3) fp32 -> bf16 [t][kc4][nt][lane][8] ----------------
// for mfma_f32_32x32x16_bf16 B-frag: col(oc) = nt*32 + (lane&31), k(ci) = kc4*16 + (lane>>5)*8 + j
__global__ void k_wpack(const float* __restrict__ w, short* __restrict__ wp){
    int i = blockIdx.x*256 + threadIdx.x;       // 27*4*2*64 = 13824
    if (i >= 27*4*2*64) return;
    int l  = i & 63;
    int nt = (i>>6) & 1;
    int kc = (i>>7) & 3;
    int t  = i>>9;
    int oc = nt*32 + (l&31);
    int cib = kc*16 + (l>>5)*8;
    ushort out[8];
    #pragma unroll
    for (int j=0;j<8;j++) out[j] = f2bf(w[((oc*CO + cib + j))*27 + t]);
    *(uint4*)(wp + (size_t)i*8) = *(uint4*)out;
}

// ---------------- AdaIN params ----------------
__global__ void k_adain(const float* __restrict__ style, const float* __restrict__ w_as,
                        const float* __restrict__ b_as, const float* __restrict__ w_ab,
                        const float* __restrict__ b_ab, float* __restrict__ sout,
                        float* __restrict__ bout){
    int t = threadIdx.x;            // 256 = B*CO
    int b = t >> 6, o = t & 63;
    const float* st = style + b*SD;
    float accs = b_as[o], accb = b_ab[o];
    for (int k=0;k<SD;k++){ float sv = st[k]; accs += sv*w_as[o*SD+k]; accb += sv*w_ab[o*SD+k]; }
    sout[t]=accs; bout[t]=accb;
}

// ---------------- per-batch coord min/max ----------------
__global__ void k_minmax(const float* __restrict__ coords, float* __restrict__ vmm){
    int b = blockIdx.x; int t = threadIdx.x;
    float mn[3]={1e30f,1e30f,1e30f}, mx[3]={-1e30f,-1e30f,-1e30f};
    const float* cp = coords + (size_t)b*NP*3;
    for (int n=t;n<NP;n+=256){
        #pragma unroll
        for(int d=0;d<3;d++){ float v = cp[n*3+d]; mn[d]=fminf(mn[d],v); mx[d]=fmaxf(mx[d],v);}
    }
    __shared__ float smn[256][3], smx[256][3];
    #pragma unroll
    for(int d=0;d<3;d++){ smn[t][d]=mn[d]; smx[t][d]=mx[d]; }
    __syncthreads();
    for(int s=128;s>0;s>>=1){
        if(t<s){
            #pragma unroll
            for(int d=0;d<3;d++){
                smn[t][d]=fminf(smn[t][d],smn[t+s][d]);
                smx[t][d]=fmaxf(smx[t][d],smx[t+s][d]);
            }
        }
        __syncthreads();
    }
    if(t<3){ vmm[b*6+t]=smn[0][t]; vmm[b*6+3+t]=smx[0][t]; }
}

// ---------------- point_in conv1x1 (pre-GN, bf16 out) + GN stats ----------------
__global__ __launch_bounds__(256) void k_pin(const float* __restrict__ feats, const float* __restrict__ w_pin,
                      ushort* __restrict__ ybuf, float* __restrict__ stats){
    __shared__ float wl[CO*CIN];
    __shared__ float sred[GRP*2];
    int t = threadIdx.x;
    for (int i=t;i<CO*CIN;i+=256) wl[i]=w_pin[i];
    if (t<GRP*2) sred[t]=0.f;
    __syncthreads();
    int p = blockIdx.x*256 + t;
    int b = p >> 15;
    int n = p & (NP-1);
    const float* fp = feats + (size_t)b*CIN*NP + n;
    float f[CIN];
    #pragma unroll
    for(int c=0;c<CIN;c++) f[c]=fp[(size_t)c*NP];
    ushort* yo = ybuf + (size_t)p*CO;
    for (int og=0;og<GRP;og++){
        float gs=0.f, gq=0.f;
        ushort vals[8];
        #pragma unroll
        for (int j=0;j<CPG;j++){
            int o = og*CPG + j;
            float acc=0.f;
            #pragma unroll
            for(int c=0;c<CIN;c++) acc += wl[o*CIN+c]*f[c];
            vals[j]=f2bf(acc); gs+=acc; gq+=acc*acc;
        }
        *(uint4*)(yo + og*CPG) = *(uint4*)vals;
        #pragma unroll
        for (int off=32; off>=1; off>>=1){ gs += __shfl_down(gs, off); gq += __shfl_down(gq, off); }
        if ((t&63)==0){ atomicAdd(&sred[og*2], gs); atomicAdd(&sred[og*2+1], gq); }
    }
    __syncthreads();
    if (t<GRP){ atomicAdd(&stats[(b*GRP+t)*2], sred[t*2]); atomicAdd(&stats[(b*GRP+t)*2+1], sred[t*2+1]); }
}

// ---------------- voxel id per point + per-voxel count ----------------
__global__ __launch_bounds__(256) void k_count(const float* __restrict__ coords, const float* __restrict__ vmm,
                        int* __restrict__ pid, int* __restrict__ cnt){
    int p = blockIdx.x*256 + threadIdx.x;
    int b = p >> 15, n = p & (NP-1);
    const float* cp = coords + (size_t)(b*NP + n)*3;
    int id[3];
    #pragma unroll
    for(int d=0;d<3;d++){
        float vmin = vmm[b*6+d], vmax = vmm[b*6+3+d];
        float nr = (cp[d]-vmin)/fmaxf(vmax-vmin,1e-8f)*(RR-1);
        int ii = (int)rintf(nr);
        id[d] = min(max(ii,0),RR-1);
    }
    int flat = (id[0]*RR + id[1])*RR + id[2];
    pid[p] = flat;
    atomicAdd(&cnt[(b<<15)+flat], 1);
}

// ---------------- per-batch exclusive scan of 32768 counts ----------------
__global__ __launch_bounds__(1024) void k_scan(const int* __restrict__ cnt, int* __restrict__ offs,
                        int* __restrict__ cursor){
    int b = blockIdx.x, t = threadIdx.x;
    const int* c = cnt + (b<<15);
    int base = t*32;
    int pref[32];
    int s = 0;
    #pragma unroll
    for (int k4=0;k4<8;k4++){
        int4 q = *(const int4*)(c + base + k4*4);
        pref[k4*4+0]=s; s+=q.x;
        pref[k4*4+1]=s; s+=q.y;
        pref[k4*4+2]=s; s+=q.z;
        pref[k4*4+3]=s; s+=q.w;
    }
    int lane = t & 63, w = t >> 6;
    int inc = s;
    #pragma unroll
    for (int off=1; off<64; off<<=1){ int u = __shfl_up(inc, off); if (lane>=off) inc += u; }
    __shared__ int wsum[16];
    if (lane==63) wsum[w]=inc;
    __syncthreads();
    int wexcl=0;
    for (int i=0;i<w;i++) wexcl += wsum[i];
    int texcl = wexcl + inc - s;
    int* o = offs + (b<<15) + base;
    int* cu = cursor + (b<<15) + base;
    #pragma unroll
    for (int k=0;k<32;k++){ int v = texcl + pref[k]; o[k]=v; cu[k]=v; }
}

// ---------------- place point indices into CSR order ----------------
__global__ __launch_bounds__(256) void k_fill(const int* __restrict__ pid, int* __restrict__ cursor,
                       int* __restrict__ order){
    int p = blockIdx.x*256 + threadIdx.x;
    int b = p >> 15, n = p & (NP-1);
    int v = pid[p];
    int slot = atomicAdd(&cursor[(b<<15)+v], 1);
    order[(b<<15)+slot] = n;
}

// ---------------- gather per voxel: GN+SiLU(y) average -> padded bf16 volume ----------------
__global__ __launch_bounds__(256) void k_gather_pad(const ushort* __restrict__ ybuf, const int* __restrict__ offs,
                             const int* __restrict__ order, const float* __restrict__ stats,
                             const float* __restrict__ gamma, const float* __restrict__ beta,
                             ushort* __restrict__ P){
    int i = blockIdx.x*256 + threadIdx.x;   // RB*NVOX*8
    int c8 = i & 7;
    int vox = (i>>3) & (NVOX-1);
    int b = i >> 18;
    float s = stats[(b*GRP+c8)*2], qq = stats[(b*GRP+c8)*2+1];
    float m = s/GN_CNT;
    float inv = rsqrtf(qq/GN_CNT - m*m + 1e-5f);
    float ga[8], be[8];
    #pragma unroll
    for (int k=0;k<8;k++){ ga[k]=gamma[c8*8+k]*inv; be[k]=beta[c8*8+k]-m*ga[k]; }
    int o0 = offs[(b<<15)+vox];
    int o1 = (vox==NVOX-1) ? NP : offs[(b<<15)+vox+1];
    float acc[8];
    #pragma unroll
    for (int k=0;k<8;k++) acc[k]=0.f;
    for (int j=o0; j<o1; j++){
        int n = order[(b<<15)+j];
        uint4 raw = *(const uint4*)(ybuf + ((size_t)((b<<15)+n))*CO + c8*8);
        ushort* us = (ushort*)&raw;
        #pragma unroll
        for (int k=0;k<8;k++){
            float x = bf2f(us[k])*ga[k] + be[k];
            acc[k] += silu_f(x);
        }
    }
    float rc = (o1>o0) ? 1.f/(float)(o1-o0) : 0.f;
    ushort out[8];
    #pragma unroll
    for (int k=0;k<8;k++) out[k]=f2bf(acc[k]*rc);
    int u = vox>>10, v = (vox>>5)&31, w = vox&31;
    size_t pd = ((size_t)b*PVOL) + (size_t)(u+1)*PSLICE + (v+1)*PROW + (w+1)*CO + c8*8;
    *(uint4*)(P + pd) = *(uint4*)out;
}

// ---------------- MFMA conv3d (32x32x16): (u, 4 v-rows) per 512-thread block ----------------
// 8 waves = 4 v-rows x 2 oc-halves; one 32x32 acc tile/wave; fully unrolled 27x4 K-loop
__global__ __launch_bounds__(512, 4) void k_conv_mfma(const __hip_bfloat16* __restrict__ P,
                        const short* __restrict__ wpack,
                        __hip_bfloat16* __restrict__ outv, float* __restrict__ stats){
    __shared__ __align__(16) char lds[18*PR*CO*2];   // 18 rows * 34 vox * 64ch bf16 = 78336 B
    int t = threadIdx.x;
    int blk = blockIdx.x;                 // ((b*32+u)*8 + vt)
    int vt = blk & 7;
    int u  = (blk >> 3) & 31;
    int b  = blk >> 8;
    int v0 = vt*4;                        // first output v of this block

    // ---- stage 18 padded rows (u..u+2, v0..v0+5) into LDS with XOR swizzle ----
    const ushort* Pp = (const ushort*)P;
    for (int i = t; i < 18*272; i += 512){
        int r = i / 272;                  // 0..17
        int chunk = i - r*272;
        int ur = r / 6, vr = r - ur*6;
        size_t src = (size_t)b*PVOL + (size_t)(u+ur)*PSLICE + (size_t)(v0+vr)*PROW + (size_t)chunk*8;
        uint4 val = *(const uint4*)(Pp + src);
        int vx = chunk >> 3;
        int colb = (chunk & 7) << 4;
        int dst = r*4352 + vx*128 + (colb ^ ((vx&7)<<4));
        *(uint4*)(lds + dst) = val;
    }
    __syncthreads();

    int l  = t & 63;
    int wv = t >> 6;                      // 0..7
    int mg = wv >> 1;                     // v-row 0..3
    int nt = wv & 1;                      // oc half (32 oc)
    int lr = l & 31;                      // A: vox row   B: oc col
    int lh = l >> 5;                      // k-half (8 elems)

    f32x16 acc = {};

    const short* wp = wpack + ((size_t)nt*64 + l)*8;   // [t][kc4][nt][lane][8]
    #pragma unroll
    for (int dz = 0; dz < 3; dz++){
      #pragma unroll
      for (int dy = 0; dy < 3; dy++){
        int row = dz*6 + mg + dy;         // LDS row
        int rb = row*4352;
        #pragma unroll
        for (int dx = 0; dx < 3; dx++){
          int tap = (dz*3 + dy)*3 + dx;
          int vx = lr + dx;
          int sw = (vx & 7) << 4;
          int base = rb + vx*128;
          #pragma unroll
          for (int kc = 0; kc < 4; kc++){
            short8 bw = *(const short8*)(wp + (size_t)(tap*4 + kc)*1024);
            short8 av = *(const short8*)(lds + base + ((kc*32 + lh*16) ^ sw));
            acc = __builtin_amdgcn_mfma_f32_32x32x16_bf16(av, bw, acc, 0, 0, 0);
          }
        }
      }
    }

    // ---- store raw bf16 + GN stats ----
    // D layout (32x32): col(oc)=lane&31, row(x)=(reg&3)+8*(reg>>2)+4*(lane>>5)
    int oc = nt*32 + lr;
    ushort* ob = (ushort*)outv;
    float s = 0.f, q = 0.f;
    size_t vrow = ((size_t)(b*32 + u)*32 + v0 + mg);
    #pragma unroll
    for (int reg = 0; reg < 16; reg++){
        float vv = acc[reg];
        s += vv; q += vv*vv;
        int x = (reg&3) + 8*(reg>>2) + 4*lh;
        ob[(vrow*32 + x)*CO + oc] = f2bf(vv);
    }
    #pragma unroll
    for (int off : {1,2,4,32}){ s += __shfl_xor(s, off); q += __shfl_xor(q, off); }
    if (lh==0 && (lr&7)==0){
        int g = nt*4 + (lr>>3);
        atomicAdd(&stats[(b*GRP+g)*2],   s);
        atomicAdd(&stats[(b*GRP+g)*2+1], q);
    }
}

// ---------------- GN finalize + SiLU + cast into padded bf16 volume ----------------
__global__ __launch_bounds__(256) void k_gnfin_cast(const __hip_bfloat16* __restrict__ raw, const float* __restrict__ stats,
                        const float* __restrict__ gamma, const float* __restrict__ beta,
                        __hip_bfloat16* __restrict__ P){
    int i = blockIdx.x*256 + threadIdx.x;
    int c8 = i & 7;
    int vox = (i>>3) & (NVOX-1);
    int b = i >> 18;
    float s = stats[(b*GRP+c8)*2], qq = stats[(b*GRP+c8)*2+1];
    float m = s/GN_CNT;
    float inv = rsqrtf(qq/GN_CNT - m*m + 1e-5f);
    uint4 rv = *(const uint4*)((const ushort*)raw + ((size_t)i)*8);
    ushort* us = (ushort*)&rv;
    ushort out[8];
    #pragma unroll
    for (int j=0;j<8;j++){
        int c = c8*8+j;
        float x = (bf2f(us[j]) - m)*inv*gamma[c] + beta[c];
        out[j] = f2bf(silu_f(x));
    }
    int u = vox>>10, v = (vox>>5)&31, w = vox&31;
    size_t pd = ((size_t)b*PVOL) + (size_t)(u+1)*PSLICE + (v+1)*PROW + (w+1)*CO + c8*8;
    *(uint4*)((ushort*)P + pd) = *(uint4*)out;
}

// ---------------- GN finalize + SiLU, bf16 in place ----------------
__global__ __launch_bounds__(256) void k_gnfin_b16(__hip_bfloat16* __restrict__ raw, const float* __restrict__ stats,
                        const float* __restrict__ gamma, const float* __restrict__ beta){
    int i = blockIdx.x*256 + threadIdx.x;
    int c8 = i & 7;
    int b = i >> 18;
    float s = stats[(b*GRP+c8)*2], qq = stats[(b*GRP+c8)*2+1];
    float m = s/GN_CNT;
    float inv = rsqrtf(qq/GN_CNT - m*m + 1e-5f);
    uint4 rv = *(const uint4*)((const ushort*)raw + ((size_t)i)*8);
    ushort* us = (ushort*)&rv;
    ushort out[8];
    #pragma unroll
    for (int j=0;j<8;j++){
        int c = c8*8+j;
        float x = (bf2f(us[j]) - m)*inv*gamma[c] + beta[c];
        out[j] = f2bf(silu_f(x));
    }
    *(uint4*)((ushort*)raw + ((size_t)i)*8) = *(uint4*)out;
}

// ---------------- devoxelize (bf16 gather) + fuse conv1x1 (pre-GN, bf16 out) + stats ----------------
__global__ __launch_bounds__(256) void k_devox_fuse(const __hip_bfloat16* __restrict__ vox, const float* __restrict__ coords,
                             const float* __restrict__ vmm, const float* __restrict__ wf,
                             ushort* __restrict__ obuf, float* __restrict__ stats){
    __shared__ float wl[CO*CO];
    __shared__ float sred[GRP*2];
    int t = threadIdx.x;
    for (int i=t;i<CO*CO;i+=256) wl[i]=wf[i];
    if (t<GRP*2) sred[t]=0.f;
    __syncthreads();
    int p = blockIdx.x*256+t;
    int b = p>>15, n = p&(NP-1);
    const float* cp = coords + (size_t)(b*NP+n)*3;
    float fr[3]; int x0[3];
    #pragma unroll
    for(int d=0;d<3;d++){
        float vmin=vmm[b*6+d], vmax=vmm[b*6+3+d];
        float nr = (cp[d]-vmin)/fmaxf(vmax-vmin,1e-8f)*(RR-1);
        nr = fminf(fmaxf(nr,0.f),(float)(RR-1));
        float fl = floorf(nr);
        x0[d]=(int)fl; fr[d]=nr-fl;
    }
    float dev[CO];
    #pragma unroll
    for(int c=0;c<CO;c++) dev[c]=0.f;
    #pragma unroll
    for (int k=0;k<8;k++){
        int d0=(k>>2)&1, d1=(k>>1)&1, d2=k&1;
        int i0=min(x0[0]+d0,RR-1), i1=min(x0[1]+d1,RR-1), i2=min(x0[2]+d2,RR-1);
        float w = (d0?fr[0]:1.f-fr[0])*(d1?fr[1]:1.f-fr[1])*(d2?fr[2]:1.f-fr[2]);
        const ushort* vp = (const ushort*)vox + ((size_t)(b*NVOX) + (i0*RR+i1)*RR+i2)*CO;
        #pragma unroll
        for (int cc=0; cc<8; cc++){
            uint4 raw = *(const uint4*)(vp + cc*8);
            ushort* us = (ushort*)&raw;
            #pragma unroll
            for (int j=0;j<8;j++) dev[cc*8+j] += w * bf2f(us[j]);
        }
    }
    ushort* op = obuf + (size_t)p*CO;
    for (int og=0;og<GRP;og++){
        float gs=0.f,gq=0.f;
        ushort vals[8];
        #pragma unroll
        for(int j=0;j<CPG;j++){
            int o=og*CPG+j;
            float acc=0.f;
            #pragma unroll
            for(int c=0;c<CO;c++) acc+=wl[o*CO+c]*dev[c];
            vals[j]=f2bf(acc); gs+=acc; gq+=acc*acc;
        }
        *(uint4*)(op+og*CPG) = *(uint4*)vals;
        #pragma unroll
        for(int off=32;off>=1;off>>=1){ gs+=__shfl_down(gs,off); gq+=__shfl_down(gq,off); }
        if((t&63)==0){ atomicAdd(&sred[og*2],gs); atomicAdd(&sred[og*2+1],gq); }
    }
    __syncthreads();
    if(t<GRP){ atomicAdd(&stats[(b*GRP+t)*2], sred[t*2]); atomicAdd(&stats[(b*GRP+t)*2+1], sred[t*2+1]); }
}

// ---------------- final: GN+SiLU + skip conv + AdaIN, write (B,C,N) ----------------
__global__ __launch_bounds__(256) void k_final(const ushort* __restrict__ obuf, const float* __restrict__ stats,
                        const float* __restrict__ gamma, const float* __restrict__ beta,
                        const float* __restrict__ feats, const float* __restrict__ wskip,
                        const float* __restrict__ ada_s, const float* __restrict__ ada_b,
                        float* __restrict__ out){
    __shared__ float wl[CO*CIN];
    int t=threadIdx.x;
    for(int i=t;i<CO*CIN;i+=256) wl[i]=wskip[i];
    __syncthreads();
    int p = blockIdx.x*256+t;
    int b=p>>15, n=p&(NP-1);
    float mean[GRP], inv[GRP];
    #pragma unroll
    for(int g=0;g<GRP;g++){
        float s=stats[(b*GRP+g)*2], q=stats[(b*GRP+g)*2+1];
        float m=s/GN_CNT;
        float v=q/GN_CNT-m*m;
        mean[g]=m; inv[g]=rsqrtf(v+1e-5f);
    }
    float f[CIN];
    const float* fp=feats + (size_t)b*CIN*NP + n;
    #pragma unroll
    for(int c=0;c<CIN;c++) f[c]=fp[(size_t)c*NP];
    float iv[CO];
    const ushort* ip = obuf + (size_t)p*CO;
    #pragma unroll
    for (int cc=0;cc<8;cc++){
        uint4 raw = *(const uint4*)(ip + cc*8);
        ushort* us = (ushort*)&raw;
        #pragma unroll
        for (int j=0;j<8;j++) iv[cc*8+j]=bf2f(us[j]);
    }
    float* op = out + (size_t)b*CO*NP + n;
    for(int o=0;o<CO;o++){
        int g=o>>3;
        float u=(iv[o]-mean[g])*inv[g]*gamma[o]+beta[o];
        u=silu_f(u);
        float sk=0.f;
        #pragma unroll
        for(int c=0;c<CIN;c++) sk+=wl[o*CIN+c]*f[c];
        float s=ada_s[b*CO+o], bb=ada_b[b*CO+o];
        op[(size_t)o*NP] = (u+sk)*(1.f+s)+bb;
    }
}

extern "C" void kernel_launch(void* const* d_in, const int* in_sizes, int n_in,
                              void* d_out, int out_size, void* d_ws, size_t ws_size,
                              hipStream_t stream){
    const float* feats =(const float*)d_in[0];
    const float* coords=(const float*)d_in[1];
    const float* style =(const float*)d_in[2];
    const float* w_pin =(const float*)d_in[3];
    const float* g_pin =(const float*)d_in[4];
    const float* b_pin =(const float*)d_in[5];
    const float* w_v1  =(const float*)d_in[6];
    const float* g_v1  =(const float*)d_in[7];
    const float* b_v1  =(const float*)d_in[8];
    const float* w_v2  =(const float*)d_in[9];
    const float* g_v2  =(const float*)d_in[10];
    const float* b_v2  =(const float*)d_in[11];
    const float* w_fuse=(const float*)d_in[12];
    const float* g_f   =(const float*)d_in[13];
    const float* b_f   =(const float*)d_in[14];
    const float* w_skip=(const float*)d_in[15];
    const float* w_as  =(const float*)d_in[16];
    const float* b_as  =(const float*)d_in[17];
    const float* w_ab  =(const float*)d_in[18];
    const float* b_ab  =(const float*)d_in[19];
    float* out=(float*)d_out;
    char* ws =(char*)d_ws;

    // workspace layout (bytes)
    ushort* ybuf  = (ushort*)ws;                            // 16.7 MB (aliased later by obuf)
    ushort* Pvol  = (ushort*)(ws + 16777216);               // 20.1 MB
    ushort* raw   = (ushort*)(ws + 16777216 + 20123648);    // 16.7 MB
    char*   small = ws + 16777216 + 20123648 + 16777216;
    float* stats  = (float*)small;                          // 256 floats
    float* vmm    = stats + 256;                            // 24
    float* ada_s  = vmm + 24;                               // 256
    float* ada_b  = ada_s + RB*CO;                          // 256
    short* wp1    = (short*)(ada_b + RB*CO);                // 110592 shorts
    short* wp2    = wp1 + 27*4*2*64*8;                      // 110592 shorts
    int*   pid    = (int*)(wp2 + 27*4*2*64*8);              // RB*NP
    int*   cnt    = pid + RB*NP;                            // RB*NVOX
    int*   offs   = cnt + RB*NVOX;                          // RB*NVOX
    int*   cursor = offs + RB*NVOX;                         // RB*NVOX
    int*   order  = cursor + RB*NVOX;                       // RB*NP
    ushort* obuf  = ybuf;                                   // reuse after gather

    float* st0 = stats;
    float* st1 = stats + 64;
    float* st2 = stats + 128;
    float* st3 = stats + 192;

    hipMemsetAsync(stats, 0, 256*sizeof(float), stream);
    hipMemsetAsync(cnt, 0, (size_t)RB*NVOX*sizeof(int), stream);
    hipMemsetAsync(Pvol, 0, (size_t)RB*PVOL*sizeof(ushort), stream);

    k_wpack<<<54,256,0,stream>>>(w_v1, wp1);
    k_wpack<<<54,256,0,stream>>>(w_v2, wp2);
    k_adain<<<1,256,0,stream>>>(style,w_as,b_as,w_ab,b_ab,ada_s,ada_b);
    k_minmax<<<RB,256,0,stream>>>(coords,vmm);

    k_pin<<<RB*NP/256,256,0,stream>>>(feats,w_pin,ybuf,st0);
    k_count<<<RB*NP/256,256,0,stream>>>(coords,vmm,pid,cnt);
    k_scan<<<RB,1024,0,stream>>>(cnt,offs,cursor);
    k_fill<<<RB*NP/256,256,0,stream>>>(pid,cursor,order);
    k_gather_pad<<<RB*NVOX*8/256,256,0,stream>>>(ybuf,offs,order,st0,g_pin,b_pin,Pvol);

    k_conv_mfma<<<RB*RR*8,512,0,stream>>>((const __hip_bfloat16*)Pvol, wp1, (__hip_bfloat16*)raw, st1);
    k_gnfin_cast<<<RB*NVOX*8/256,256,0,stream>>>((const __hip_bfloat16*)raw, st1, g_v1, b_v1, (__hip_bfloat16*)Pvol);
    k_conv_mfma<<<RB*RR*8,512,0,stream>>>((const __hip_bfloat16*)Pvol, wp2, (__hip_bfloat16*)raw, st2);
    k_gnfin_b16<<<RB*NVOX*8/256,256,0,stream>>>((__hip_bfloat16*)raw, st2, g_v2, b_v2);

    k_devox_fuse<<<RB*NP/256,256,0,stream>>>((const __hip_bfloat16*)raw, coords, vmm, w_fuse, obuf, st3);
    k_final<<<RB*NP/256,256,0,stream>>>(obuf, st3, g_f, b_f, feats, w_skip, ada_s, ada_b, out);
}

// Round 6
// 482.329 us; speedup vs baseline: 7.7928x; 1.2122x over previous
//
#include <hip/hip_runtime.h>
#include <hip/hip_bf16.h>
#include <math.h>

#define RR   32
#define RB   4
#define CIN  32
#define CO   64
#define NP   32768
#define SD   256
#define NVOX (RR*RR*RR)       // 32768
#define GRP  8
#define CPG  8
#define GN_CNT 262144.0f      // 8 ch * 32768 vox per group
#define PR   34               // padded resolution
#define PSLICE (PR*PR*CO)     // 73984   (U stride)
#define PROW   (PR*CO)        // 2176    (V stride)
#define PVOL   ((size_t)PR*PR*PR*CO)   // per-batch padded elems 2,515,456
#define WSL   73728           // 72KB of weights per dz slice (9 taps x 4 kc x 2 nt x 1KB)

typedef __attribute__((ext_vector_type(8))) short short8;
typedef __attribute__((ext_vector_type(4))) float f32x4;
typedef __attribute__((ext_vector_type(16))) float f32x16;

__device__ inline float silu_f(float x){ return x / (1.f + __expf(-x)); }
__device__ inline float bf2f(ushort u){ uint v = ((uint)u)<<16; return *(float*)&v; }
__device__ inline ushort f2bf(float x){ __hip_bfloat16 h = __float2bfloat16(x); return *(ushort*)&h; }

// ---------------- weight pack: (O,I,3,3,3) fp32 -> bf16 [t][kc4][nt][lane][8] ----------------
// for mfma_f32_32x32x16_bf16 B-frag: col(oc) = nt*32 + (lane&31), k(ci) = kc4*16 + (lane>>5)*8 + j
__global__ void k_wpack(const float* __restrict__ w, short* __restrict__ wp){
    int i = blockIdx.x*256 + threadIdx.x;       // 27*4*2*64 = 13824
    if (i >= 27*4*2*64) return;
    int l  = i & 63;
    int nt = (i>>6) & 1;
    int kc = (i>>7) & 3;
    int t  = i>>9;
    int oc = nt*32 + (l&31);
    int cib = kc*16 + (l>>5)*8;
    ushort out[8];
    #pragma unroll
    for (int j=0;j<8;j++) out[j] = f2bf(w[((oc*CO + cib + j))*27 + t]);
    *(uint4*)(wp + (size_t)i*8) = *(uint4*)out;
}

// ---------------- AdaIN params ----------------
__global__ void k_adain(const float* __restrict__ style, const float* __restrict__ w_as,
                        const float* __restrict__ b_as, const float* __restrict__ w_ab,
                        const float* __restrict__ b_ab, float* __restrict__ sout,
                        float* __restrict__ bout){
    int t = threadIdx.x;            // 256 = B*CO
    int b = t >> 6, o = t & 63;
    const float* st = style + b*SD;
    float accs = b_as[o], accb = b_ab[o];
    for (int k=0;k<SD;k++){ float sv = st[k]; accs += sv*w_as[o*SD+k]; accb += sv*w_ab[o*SD+k]; }
    sout[t]=accs; bout[t]=accb;
}

// ---------------- per-batch coord min/max ----------------
__global__ void k_minmax(const float* __restrict__ coords, float* __restrict__ vmm){
    int b = blockIdx.x; int t = threadIdx.x;
    float mn[3]={1e30f,1e30f,1e30f}, mx[3]={-1e30f,-1e30f,-1e30f};
    const float* cp = coords + (size_t)b*NP*3;
    for (int n=t;n<NP;n+=256){
        #pragma unroll
        for(int d=0;d<3;d++){ float v = cp[n*3+d]; mn[d]=fminf(mn[d],v); mx[d]=fmaxf(mx[d],v);}
    }
    __shared__ float smn[256][3], smx[256][3];
    #pragma unroll
    for(int d=0;d<3;d++){ smn[t][d]=mn[d]; smx[t][d]=mx[d]; }
    __syncthreads();
    for(int s=128;s>0;s>>=1){
        if(t<s){
            #pragma unroll
            for(int d=0;d<3;d++){
                smn[t][d]=fminf(smn[t][d],smn[t+s][d]);
                smx[t][d]=fmaxf(smx[t][d],smx[t+s][d]);
            }
        }
        __syncthreads();
    }
    if(t<3){ vmm[b*6+t]=smn[0][t]; vmm[b*6+3+t]=smx[0][t]; }
}

// ---------------- point_in conv1x1 (pre-GN, bf16 out) + GN stats ----------------
__global__ __launch_bounds__(256) void k_pin(const float* __restrict__ feats, const float* __restrict__ w_pin,
                      ushort* __restrict__ ybuf, float* __restrict__ stats){
    __shared__ float wl[CO*CIN];
    __shared__ float sred[GRP*2];
    int t = threadIdx.x;
    for (int i=t;i<CO*CIN;i+=256) wl[i]=w_pin[i];
    if (t<GRP*2) sred[t]=0.f;
    __syncthreads();
    int p = blockIdx.x*256 + t;
    int b = p >> 15;
    int n = p & (NP-1);
    const float* fp = feats + (size_t)b*CIN*NP + n;
    float f[CIN];
    #pragma unroll
    for(int c=0;c<CIN;c++) f[c]=fp[(size_t)c*NP];
    ushort* yo = ybuf + (size_t)p*CO;
    for (int og=0;og<GRP;og++){
        float gs=0.f, gq=0.f;
        ushort vals[8];
        #pragma unroll
        for (int j=0;j<CPG;j++){
            int o = og*CPG + j;
            float acc=0.f;
            #pragma unroll
            for(int c=0;c<CIN;c++) acc += wl[o*CIN+c]*f[c];
            vals[j]=f2bf(acc); gs+=acc; gq+=acc*acc;
        }
        *(uint4*)(yo + og*CPG) = *(uint4*)vals;
        #pragma unroll
        for (int off=32; off>=1; off>>=1){ gs += __shfl_down(gs, off); gq += __shfl_down(gq, off); }
        if ((t&63)==0){ atomicAdd(&sred[og*2], gs); atomicAdd(&sred[og*2+1], gq); }
    }
    __syncthreads();
    if (t<GRP){ atomicAdd(&stats[(b*GRP+t)*2], sred[t*2]); atomicAdd(&stats[(b*GRP+t)*2+1], sred[t*2+1]); }
}

// ---------------- voxel id per point + per-voxel count ----------------
__global__ __launch_bounds__(256) void k_count(const float* __restrict__ coords, const float* __restrict__ vmm,
                        int* __restrict__ pid, int* __restrict__ cnt){
    int p = blockIdx.x*256 + threadIdx.x;
    int b = p >> 15, n = p & (NP-1);
    const float* cp = coords + (size_t)(b*NP + n)*3;
    int id[3];
    #pragma unroll
    for(int d=0;d<3;d++){
        float vmin = vmm[b*6+d], vmax = vmm[b*6+3+d];
        float nr = (cp[d]-vmin)/fmaxf(vmax-vmin,1e-8f)*(RR-1);
        int ii = (int)rintf(nr);
        id[d] = min(max(ii,0),RR-1);
    }
    int flat = (id[0]*RR + id[1])*RR + id[2];
    pid[p] = flat;
    atomicAdd(&cnt[(b<<15)+flat], 1);
}

// ---------------- per-batch exclusive scan of 32768 counts ----------------
__global__ __launch_bounds__(1024) void k_scan(const int* __restrict__ cnt, int* __restrict__ offs,
                        int* __restrict__ cursor){
    int b = blockIdx.x, t = threadIdx.x;
    const int* c = cnt + (b<<15);
    int base = t*32;
    int pref[32];
    int s = 0;
    #pragma unroll
    for (int k4=0;k4<8;k4++){
        int4 q = *(const int4*)(c + base + k4*4);
        pref[k4*4+0]=s; s+=q.x;
        pref[k4*4+1]=s; s+=q.y;
        pref[k4*4+2]=s; s+=q.z;
        pref[k4*4+3]=s; s+=q.w;
    }
    int lane = t & 63, w = t >> 6;
    int inc = s;
    #pragma unroll
    for (int off=1; off<64; off<<=1){ int u = __shfl_up(inc, off); if (lane>=off) inc += u; }
    __shared__ int wsum[16];
    if (lane==63) wsum[w]=inc;
    __syncthreads();
    int wexcl=0;
    for (int i=0;i<w;i++) wexcl += wsum[i];
    int texcl = wexcl + inc - s;
    int* o = offs + (b<<15) + base;
    int* cu = cursor + (b<<15) + base;
    #pragma unroll
    for (int k=0;k<32;k++){ int v = texcl + pref[k]; o[k]=v; cu[k]=v; }
}

// ---------------- place point indices into CSR order ----------------
__global__ __launch_bounds__(256) void k_fill(const int* __restrict__ pid, int* __restrict__ cursor,
                       int* __restrict__ order){
    int p = blockIdx.x*256 + threadIdx.x;
    int b = p >> 15, n = p & (NP-1);
    int v = pid[p];
    int slot = atomicAdd(&cursor[(b<<15)+v], 1);
    order[(b<<15)+slot] = n;
}

// ---------------- gather per voxel: GN+SiLU(y) average -> padded bf16 volume ----------------
__global__ __launch_bounds__(256) void k_gather_pad(const ushort* __restrict__ ybuf, const int* __restrict__ offs,
                             const int* __restrict__ order, const float* __restrict__ stats,
                             const float* __restrict__ gamma, const float* __restrict__ beta,
                             ushort* __restrict__ P){
    int i = blockIdx.x*256 + threadIdx.x;   // RB*NVOX*8
    int c8 = i & 7;
    int vox = (i>>3) & (NVOX-1);
    int b = i >> 18;
    float s = stats[(b*GRP+c8)*2], qq = stats[(b*GRP+c8)*2+1];
    float m = s/GN_CNT;
    float inv = rsqrtf(qq/GN_CNT - m*m + 1e-5f);
    float ga[8], be[8];
    #pragma unroll
    for (int k=0;k<8;k++){ ga[k]=gamma[c8*8+k]*inv; be[k]=beta[c8*8+k]-m*ga[k]; }
    int o0 = offs[(b<<15)+vox];
    int o1 = (vox==NVOX-1) ? NP : offs[(b<<15)+vox+1];
    float acc[8];
    #pragma unroll
    for (int k=0;k<8;k++) acc[k]=0.f;
    for (int j=o0; j<o1; j++){
        int n = order[(b<<15)+j];
        uint4 raw = *(const uint4*)(ybuf + ((size_t)((b<<15)+n))*CO + c8*8);
        ushort* us = (ushort*)&raw;
        #pragma unroll
        for (int k=0;k<8;k++){
            float x = bf2f(us[k])*ga[k] + be[k];
            acc[k] += silu_f(x);
        }
    }
    float rc = (o1>o0) ? 1.f/(float)(o1-o0) : 0.f;
    ushort out[8];
    #pragma unroll
    for (int k=0;k<8;k++) out[k]=f2bf(acc[k]*rc);
    int u = vox>>10, v = (vox>>5)&31, w = vox&31;
    size_t pd = ((size_t)b*PVOL) + (size_t)(u+1)*PSLICE + (v+1)*PROW + (w+1)*CO + c8*8;
    *(uint4*)(P + pd) = *(uint4*)out;
}

// ---------------- MFMA conv3d (32x32x16): (u, 16 v-rows) per 512-thread block ----------------
// 8 waves, each = 2 v-rows x full 64 oc (2 nt tiles), 4 acc tiles -> 1 ds_read per MFMA.
// Weights staged per-dz in LDS (kills redundant L2 reads + load latency).
__global__ __launch_bounds__(512, 2) void k_conv_mfma(const __hip_bfloat16* __restrict__ P,
                        const short* __restrict__ wpack,
                        __hip_bfloat16* __restrict__ outv, float* __restrict__ stats){
    __shared__ __align__(16) char lds[18*4352 + WSL];   // 78336 act + 73728 weights = 152064 B
    char* wlds = lds + 18*4352;
    int t = threadIdx.x;
    int blk = blockIdx.x;                 // (b*32+u)*2 + vt
    int vt = blk & 1;
    int u  = (blk >> 1) & 31;
    int b  = blk >> 6;
    int v0 = vt*16;                       // first output v-row of this block

    const ushort* Pp = (const ushort*)P;
    int l  = t & 63;
    int wv = t >> 6;                      // v-pair 0..7 -> v-rows {2wv, 2wv+1}
    int lr = l & 31;                      // A row (x pos) / B col (oc)
    int lh = l >> 5;                      // k half

    f32x16 acc00 = {}, acc01 = {}, acc10 = {}, acc11 = {};   // [vl][nt]

    for (int dz = 0; dz < 3; dz++){
        if (dz) __syncthreads();          // all waves done with previous LDS contents
        // ---- stage activation slice u+dz (padded), rows v0..v0+17, XOR-swizzled ----
        for (int i = t; i < 18*272; i += 512){
            int r = i / 272;
            int chunk = i - r*272;
            size_t src = (size_t)b*PVOL + (size_t)(u+dz)*PSLICE + (size_t)(v0+r)*PROW + (size_t)chunk*8;
            uint4 val = *(const uint4*)(Pp + src);
            int vx = chunk >> 3;
            int colb = (chunk & 7) << 4;
            int dst = r*4352 + vx*128 + (colb ^ ((vx&7)<<4));
            *(uint4*)(lds + dst) = val;
        }
        // ---- stage weight slice dz: 72KB linear copy ----
        const uint4* wsrc = (const uint4*)(wpack + (size_t)dz*(WSL/2));
        uint4* wdst = (uint4*)wlds;
        for (int i = t; i < WSL/16; i += 512) wdst[i] = wsrc[i];
        __syncthreads();
        // ---- compute: 9 taps x 4 kc, 4 MFMA per iter, all operands from LDS ----
        #pragma unroll
        for (int dy = 0; dy < 3; dy++){
            int ra_base = (2*wv + dy)*4352;
            #pragma unroll
            for (int dx = 0; dx < 3; dx++){
                int vx = lr + dx;
                int sw = (vx & 7) << 4;
                int abase = ra_base + vx*128;
                int wbase = ((dy*3 + dx)*4)*2048 + l*16;
                #pragma unroll
                for (int kc = 0; kc < 4; kc++){
                    short8 bw0 = *(const short8*)(wlds + wbase + kc*2048);
                    short8 bw1 = *(const short8*)(wlds + wbase + kc*2048 + 1024);
                    int col = (kc*32 + lh*16) ^ sw;
                    short8 av0 = *(const short8*)(lds + abase + col);
                    short8 av1 = *(const short8*)(lds + abase + 4352 + col);
                    acc00 = __builtin_amdgcn_mfma_f32_32x32x16_bf16(av0, bw0, acc00, 0, 0, 0);
                    acc01 = __builtin_amdgcn_mfma_f32_32x32x16_bf16(av0, bw1, acc01, 0, 0, 0);
                    acc10 = __builtin_amdgcn_mfma_f32_32x32x16_bf16(av1, bw0, acc10, 0, 0, 0);
                    acc11 = __builtin_amdgcn_mfma_f32_32x32x16_bf16(av1, bw1, acc11, 0, 0, 0);
                }
            }
        }
    }

    // ---- store raw bf16 + GN stats ----
    // D layout (32x32): col(oc)=lane&31, row(x)=(reg&3)+8*(reg>>2)+4*(lane>>5)
    ushort* ob = (ushort*)outv;
    float s0 = 0.f, q0 = 0.f, s1 = 0.f, q1 = 0.f;
    size_t vrow0 = ((size_t)(b*32 + u)*32 + v0 + 2*wv);
    #pragma unroll
    for (int reg = 0; reg < 16; reg++){
        int x = (reg&3) + 8*(reg>>2) + 4*lh;
        float a, c;
        a = acc00[reg]; c = acc01[reg];
        s0 += a; q0 += a*a; s1 += c; q1 += c*c;
        ob[(vrow0*32 + x)*CO + lr]      = f2bf(a);
        ob[(vrow0*32 + x)*CO + 32 + lr] = f2bf(c);
        a = acc10[reg]; c = acc11[reg];
        s0 += a; q0 += a*a; s1 += c; q1 += c*c;
        ob[((vrow0+1)*32 + x)*CO + lr]      = f2bf(a);
        ob[((vrow0+1)*32 + x)*CO + 32 + lr] = f2bf(c);
    }
    #pragma unroll
    for (int off : {1,2,4,32}){
        s0 += __shfl_xor(s0, off); q0 += __shfl_xor(q0, off);
        s1 += __shfl_xor(s1, off); q1 += __shfl_xor(q1, off);
    }
    if (lh==0 && (lr&7)==0){
        int g0 = lr>>3;              // nt=0 groups 0..3
        atomicAdd(&stats[(b*GRP+g0)*2],     s0);
        atomicAdd(&stats[(b*GRP+g0)*2+1],   q0);
        atomicAdd(&stats[(b*GRP+4+g0)*2],   s1);
        atomicAdd(&stats[(b*GRP+4+g0)*2+1], q1);
    }
}

// ---------------- GN finalize + SiLU + cast into padded bf16 volume ----------------
__global__ __launch_bounds__(256) void k_gnfin_cast(const __hip_bfloat16* __restrict__ raw, const float* __restrict__ stats,
                        const float* __restrict__ gamma, const float* __restrict__ beta,
                        __hip_bfloat16* __restrict__ P){
    int i = blockIdx.x*256 + threadIdx.x;
    int c8 = i & 7;
    int vox = (i>>3) & (NVOX-1);
    int b = i >> 18;
    float s = stats[(b*GRP+c8)*2], qq = stats[(b*GRP+c8)*2+1];
    float m = s/GN_CNT;
    float inv = rsqrtf(qq/GN_CNT - m*m + 1e-5f);
    uint4 rv = *(const uint4*)((const ushort*)raw + ((size_t)i)*8);
    ushort* us = (ushort*)&rv;
    ushort out[8];
    #pragma unroll
    for (int j=0;j<8;j++){
        int c = c8*8+j;
        float x = (bf2f(us[j]) - m)*inv*gamma[c] + beta[c];
        out[j] = f2bf(silu_f(x));
    }
    int u = vox>>10, v = (vox>>5)&31, w = vox&31;
    size_t pd = ((size_t)b*PVOL) + (size_t)(u+1)*PSLICE + (v+1)*PROW + (w+1)*CO + c8*8;
    *(uint4*)((ushort*)P + pd) = *(uint4*)out;
}

// ---------------- GN finalize + SiLU, bf16 in place ----------------
__global__ __launch_bounds__(256) void k_gnfin_b16(__hip_bfloat16* __restrict__ raw, const float* __restrict__ stats,
                        const float* __restrict__ gamma, const float* __restrict__ beta){
    int i = blockIdx.x*256 + threadIdx.x;
    int c8 = i & 7;
    int b = i >> 18;
    float s = stats[(b*GRP+c8)*2], qq = stats[(b*GRP+c8)*2+1];
    float m = s/GN_CNT;
    float inv = rsqrtf(qq/GN_CNT - m*m + 1e-5f);
    uint4 rv = *(const uint4*)((const ushort*)raw + ((size_t)i)*8);
    ushort* us = (ushort*)&rv;
    ushort out[8];
    #pragma unroll
    for (int j=0;j<8;j++){
        int c = c8*8+j;
        float x = (bf2f(us[j]) - m)*inv*gamma[c] + beta[c];
        out[j] = f2bf(silu_f(x));
    }
    *(uint4*)((ushort*)raw + ((size_t)i)*8) = *(uint4*)out;
}

// ---------------- devoxelize (bf16 gather) + fuse conv1x1 (pre-GN, bf16 out) + stats ----------------
__global__ __launch_bounds__(256) void k_devox_fuse(const __hip_bfloat16* __restrict__ vox, const float* __restrict__ coords,
                             const float* __restrict__ vmm, const float* __restrict__ wf,
                             ushort* __restrict__ obuf, float* __restrict__ stats){
    __shared__ float wl[CO*CO];
    __shared__ float sred[GRP*2];
    int t = threadIdx.x;
    for (int i=t;i<CO*CO;i+=256) wl[i]=wf[i];
    if (t<GRP*2) sred[t]=0.f;
    __syncthreads();
    int p = blockIdx.x*256+t;
    int b = p>>15, n = p&(NP-1);
    const float* cp = coords + (size_t)(b*NP+n)*3;
    float fr[3]; int x0[3];
    #pragma unroll
    for(int d=0;d<3;d++){
        float vmin=vmm[b*6+d], vmax=vmm[b*6+3+d];
        float nr = (cp[d]-vmin)/fmaxf(vmax-vmin,1e-8f)*(RR-1);
        nr = fminf(fmaxf(nr,0.f),(float)(RR-1));
        float fl = floorf(nr);
        x0[d]=(int)fl; fr[d]=nr-fl;
    }
    float dev[CO];
    #pragma unroll
    for(int c=0;c<CO;c++) dev[c]=0.f;
    #pragma unroll
    for (int k=0;k<8;k++){
        int d0=(k>>2)&1, d1=(k>>1)&1, d2=k&1;
        int i0=min(x0[0]+d0,RR-1), i1=min(x0[1]+d1,RR-1), i2=min(x0[2]+d2,RR-1);
        float w = (d0?fr[0]:1.f-fr[0])*(d1?fr[1]:1.f-fr[1])*(d2?fr[2]:1.f-fr[2]);
        const ushort* vp = (const ushort*)vox + ((size_t)(b*NVOX) + (i0*RR+i1)*RR+i2)*CO;
        #pragma unroll
        for (int cc=0; cc<8; cc++){
            uint4 raw = *(const uint4*)(vp + cc*8);
            ushort* us = (ushort*)&raw;
            #pragma unroll
            for (int j=0;j<8;j++) dev[cc*8+j] += w * bf2f(us[j]);
        }
    }
    ushort* op = obuf + (size_t)p*CO;
    for (int og=0;og<GRP;og++){
        float gs=0.f,gq=0.f;
        ushort vals[8];
        #pragma unroll
        for(int j=0;j<CPG;j++){
            int o=og*CPG+j;
            float acc=0.f;
            #pragma unroll
            for(int c=0;c<CO;c++) acc+=wl[o*CO+c]*dev[c];
            vals[j]=f2bf(acc); gs+=acc; gq+=acc*acc;
        }
        *(uint4*)(op+og*CPG) = *(uint4*)vals;
        #pragma unroll
        for(int off=32;off>=1;off>>=1){ gs+=__shfl_down(gs,off); gq+=__shfl_down(gq,off); }
        if((t&63)==0){ atomicAdd(&sred[og*2],gs); atomicAdd(&sred[og*2+1],gq); }
    }
    __syncthreads();
    if(t<GRP){ atomicAdd(&stats[(b*GRP+t)*2], sred[t*2]); atomicAdd(&stats[(b*GRP+t)*2+1], sred[t*2+1]); }
}

// ---------------- final: GN+SiLU + skip conv + AdaIN, write (B,C,N) ----------------
__global__ __launch_bounds__(256) void k_final(const ushort* __restrict__ obuf, const float* __restrict__ stats,
                        const float* __restrict__ gamma, const float* __restrict__ beta,
                        const float* __restrict__ feats, const float* __restrict__ wskip,
                        const float* __restrict__ ada_s, const float* __restrict__ ada_b,
                        float* __restrict__ out){
    __shared__ float wl[CO*CIN];
    int t=threadIdx.x;
    for(int i=t;i<CO*CIN;i+=256) wl[i]=wskip[i];
    __syncthreads();
    int p = blockIdx.x*256+t;
    int b=p>>15, n=p&(NP-1);
    float mean[GRP], inv[GRP];
    #pragma unroll
    for(int g=0;g<GRP;g++){
        float s=stats[(b*GRP+g)*2], q=stats[(b*GRP+g)*2+1];
        float m=s/GN_CNT;
        float v=q/GN_CNT-m*m;
        mean[g]=m; inv[g]=rsqrtf(v+1e-5f);
    }
    float f[CIN];
    const float* fp=feats + (size_t)b*CIN*NP + n;
    #pragma unroll
    for(int c=0;c<CIN;c++) f[c]=fp[(size_t)c*NP];
    float iv[CO];
    const ushort* ip = obuf + (size_t)p*CO;
    #pragma unroll
    for (int cc=0;cc<8;cc++){
        uint4 raw = *(const uint4*)(ip + cc*8);
        ushort* us = (ushort*)&raw;
        #pragma unroll
        for (int j=0;j<8;j++) iv[cc*8+j]=bf2f(us[j]);
    }
    float* op = out + (size_t)b*CO*NP + n;
    for(int o=0;o<CO;o++){
        int g=o>>3;
        float u=(iv[o]-mean[g])*inv[g]*gamma[o]+beta[o];
        u=silu_f(u);
        float sk=0.f;
        #pragma unroll
        for(int c=0;c<CIN;c++) sk+=wl[o*CIN+c]*f[c];
        float s=ada_s[b*CO+o], bb=ada_b[b*CO+o];
        op[(size_t)o*NP] = (u+sk)*(1.f+s)+bb;
    }
}

extern "C" void kernel_launch(void* const* d_in, const int* in_sizes, int n_in,
                              void* d_out, int out_size, void* d_ws, size_t ws_size,
                              hipStream_t stream){
    const float* feats =(const float*)d_in[0];
    const float* coords=(const float*)d_in[1];
    const float* style =(const float*)d_in[2];
    const float* w_pin =(const float*)d_in[3];
    const float* g_pin =(const float*)d_in[4];
    const float* b_pin =(const float*)d_in[5];
    const float* w_v1  =(const float*)d_in[6];
    const float* g_v1  =(const float*)d_in[7];
    const float* b_v1  =(const float*)d_in[8];
    const float* w_v2  =(const float*)d_in[9];
    const float* g_v2  =(const float*)d_in[10];
    const float* b_v2  =(const float*)d_in[11];
    const float* w_fuse=(const float*)d_in[12];
    const float* g_f   =(const float*)d_in[13];
    const float* b_f   =(const float*)d_in[14];
    const float* w_skip=(const float*)d_in[15];
    const float* w_as  =(const float*)d_in[16];
    const float* b_as  =(const float*)d_in[17];
    const float* w_ab  =(const float*)d_in[18];
    const float* b_ab  =(const float*)d_in[19];
    float* out=(float*)d_out;
    char* ws =(char*)d_ws;

    // workspace layout (bytes)
    ushort* ybuf  = (ushort*)ws;                            // 16.7 MB (aliased later by obuf)
    ushort* Pvol  = (ushort*)(ws + 16777216);               // 20.1 MB
    ushort* raw   = (ushort*)(ws + 16777216 + 20123648);    // 16.7 MB
    char*   small = ws + 16777216 + 20123648 + 16777216;
    float* stats  = (float*)small;                          // 256 floats
    float* vmm    = stats + 256;                            // 24
    float* ada_s  = vmm + 24;                               // 256
    float* ada_b  = ada_s + RB*CO;                          // 256
    short* wp1    = (short*)(ada_b + RB*CO);                // 110592 shorts
    short* wp2    = wp1 + 27*4*2*64*8;                      // 110592 shorts
    int*   pid    = (int*)(wp2 + 27*4*2*64*8);              // RB*NP
    int*   cnt    = pid + RB*NP;                            // RB*NVOX
    int*   offs   = cnt + RB*NVOX;                          // RB*NVOX
    int*   cursor = offs + RB*NVOX;                         // RB*NVOX
    int*   order  = cursor + RB*NVOX;                       // RB*NP
    ushort* obuf  = ybuf;                                   // reuse after gather

    float* st0 = stats;
    float* st1 = stats + 64;
    float* st2 = stats + 128;
    float* st3 = stats + 192;

    hipMemsetAsync(stats, 0, 256*sizeof(float), stream);
    hipMemsetAsync(cnt, 0, (size_t)RB*NVOX*sizeof(int), stream);
    hipMemsetAsync(Pvol, 0, (size_t)RB*PVOL*sizeof(ushort), stream);

    k_wpack<<<54,256,0,stream>>>(w_v1, wp1);
    k_wpack<<<54,256,0,stream>>>(w_v2, wp2);
    k_adain<<<1,256,0,stream>>>(style,w_as,b_as,w_ab,b_ab,ada_s,ada_b);
    k_minmax<<<RB,256,0,stream>>>(coords,vmm);

    k_pin<<<RB*NP/256,256,0,stream>>>(feats,w_pin,ybuf,st0);
    k_count<<<RB*NP/256,256,0,stream>>>(coords,vmm,pid,cnt);
    k_scan<<<RB,1024,0,stream>>>(cnt,offs,cursor);
    k_fill<<<RB*NP/256,256,0,stream>>>(pid,cursor,order);
    k_gather_pad<<<RB*NVOX*8/256,256,0,stream>>>(ybuf,offs,order,st0,g_pin,b_pin,Pvol);

    k_conv_mfma<<<RB*RR*2,512,0,stream>>>((const __hip_bfloat16*)Pvol, wp1, (__hip_bfloat16*)raw, st1);
    k_gnfin_cast<<<RB*NVOX*8/256,256,0,stream>>>((const __hip_bfloat16*)raw, st1, g_v1, b_v1, (__hip_bfloat16*)Pvol);
    k_conv_mfma<<<RB*RR*2,512,0,stream>>>((const __hip_bfloat16*)Pvol, wp2, (__hip_bfloat16*)raw, st2);
    k_gnfin_b16<<<RB*NVOX*8/256,256,0,stream>>>((__hip_bfloat16*)raw, st2, g_v2, b_v2);

    k_devox_fuse<<<RB*NP/256,256,0,stream>>>((const __hip_bfloat16*)raw, coords, vmm, w_fuse, obuf, st3);
    k_final<<<RB*NP/256,256,0,stream>>>(obuf, st3, g_f, b_f, feats, w_skip, ada_s, ada_b, out);
}